// Round 7
// baseline (1407.862 us; speedup 1.0000x reference)
//
#include <hip/hip_runtime.h>
#include <cmath>

// Problem constants (from reference setup_inputs)
constexpr int T_   = 8;
constexpr int N_   = 8192;
constexpr int DEG_ = 15;
constexpr int E_   = N_ * (DEG_ + 1);   // 131072 edges per timestep
constexpr float L2E_ = 1.44269504f;

__device__ __forceinline__ float elu1(float v) { return v > 0.f ? v : expm1f(v); }

typedef __attribute__((ext_vector_type(8))) short bf16x8;
typedef __attribute__((ext_vector_type(4))) float f32x4;

__device__ __forceinline__ ushort f2bf(float x) {
  uint u = __float_as_uint(x);
  return (ushort)((u + 0x7FFFu + ((u >> 16) & 1u)) >> 16);
}
__device__ __forceinline__ float bf2f(ushort h) {
  return __uint_as_float(((uint)h) << 16);
}

// ---------------------------------------------------------------------------
// split_x: fp32 array -> hi/lo bf16 arrays (same layout). 4 elems/thread.
// ---------------------------------------------------------------------------
__global__ __launch_bounds__(256) void split_x(
    const float* __restrict__ X, ushort* __restrict__ XH, ushort* __restrict__ XL, int n4)
{
  const int i = blockIdx.x * 256 + threadIdx.x;
  if (i >= n4) return;
  const float4 v = ((const float4*)X)[i];
  const ushort h0 = f2bf(v.x), h1 = f2bf(v.y), h2 = f2bf(v.z), h3 = f2bf(v.w);
  ushort4 hh; hh.x = h0; hh.y = h1; hh.z = h2; hh.w = h3;
  ushort4 ll;
  ll.x = f2bf(v.x - bf2f(h0)); ll.y = f2bf(v.y - bf2f(h1));
  ll.z = f2bf(v.z - bf2f(h2)); ll.w = f2bf(v.w - bf2f(h3));
  ((ushort4*)XH)[i] = hh;
  ((ushort4*)XL)[i] = ll;
}

// ---------------------------------------------------------------------------
// split_wt: W_l, W_r [K, HC] fp32 -> WH/WL [2][HC][K] bf16 (transposed).
// ---------------------------------------------------------------------------
__global__ __launch_bounds__(256) void split_wt(
    const float* __restrict__ Wl, const float* __restrict__ Wr,
    ushort* __restrict__ WH, ushort* __restrict__ WL, int K, int HC)
{
  const int idx = blockIdx.x * 256 + threadIdx.x;
  if (idx >= 2 * HC * K) return;
  const int k = idx % K;
  const int n = (idx / K) % HC;
  const int s = idx / (K * HC);
  const float v = (s ? Wr : Wl)[k * HC + n];
  const ushort h = f2bf(v);
  WH[idx] = h;
  WL[idx] = f2bf(v - bf2f(h));
}

// ---------------------------------------------------------------------------
// MFMA GEMM (split-bf16): C = A @ W, A hi/lo [nt][M][K] bf16, W hi/lo
// [2][Ncol][K] bf16 (transposed). x.w ~= ah.wh + ah.wl + al.wh.
// BM=128, BN=64, BK=32; 256 thr = 4 waves.
// ---------------------------------------------------------------------------
__global__ __launch_bounds__(256) void gemm_mfma(
    const ushort* __restrict__ Ah, const ushort* __restrict__ Al,
    const ushort* __restrict__ Wh, const ushort* __restrict__ Wl,
    float* __restrict__ Cl, float* __restrict__ Cr,
    int M, int Ncol, int K, int nt)
{
  __shared__ alignas(16) ushort lAh[4 * 1032];
  __shared__ alignas(16) ushort lAl[4 * 1032];
  __shared__ alignas(16) ushort lBh[4 * 520];
  __shared__ alignas(16) ushort lBl[4 * 520];

  const int z = blockIdx.z;
  const int t = (z < nt) ? z : z - nt;
  const int side = (z < nt) ? 0 : 1;
  const ushort* __restrict__ Bh = Wh + (size_t)side * Ncol * K;
  const ushort* __restrict__ Bl = Wl + (size_t)side * Ncol * K;
  float* __restrict__ C = (side ? Cr : Cl) + (size_t)t * M * Ncol;
  const size_t aoff = (size_t)t * M * K;

  const int bm = blockIdx.x * 128, bn = blockIdx.y * 64;
  const int tid = threadIdx.x;
  const int wid = tid >> 6, lane = tid & 63;
  const int l15 = lane & 15, lk = lane >> 4;

  f32x4 acc[2][4] = {};

  for (int k0 = 0; k0 < K; k0 += 32) {
    #pragma unroll
    for (int c = 0; c < 2; c++) {
      const int ch = tid + c * 256;
      const int row = ch >> 2, kc = ch & 3;
      const size_t ga = aoff + (size_t)(bm + row) * K + (k0 + kc * 8);
      *(uint4*)&lAh[kc * 1032 + row * 8] = *(const uint4*)(Ah + ga);
      *(uint4*)&lAl[kc * 1032 + row * 8] = *(const uint4*)(Al + ga);
    }
    {
      const int col = tid >> 2, kc = tid & 3;
      const size_t gb = (size_t)(bn + col) * K + (k0 + kc * 8);
      *(uint4*)&lBh[kc * 520 + col * 8] = *(const uint4*)(Bh + gb);
      *(uint4*)&lBl[kc * 520 + col * 8] = *(const uint4*)(Bl + gb);
    }
    __syncthreads();

    bf16x8 ah[2], al[2], bh4[4], bl4[4];
    const int r0 = wid * 32;
    #pragma unroll
    for (int rf = 0; rf < 2; rf++) {
      const int ro = (r0 + rf * 16 + l15) * 8;
      ah[rf] = *(const bf16x8*)&lAh[lk * 1032 + ro];
      al[rf] = *(const bf16x8*)&lAl[lk * 1032 + ro];
    }
    #pragma unroll
    for (int cf = 0; cf < 4; cf++) {
      const int co = (cf * 16 + l15) * 8;
      bh4[cf] = *(const bf16x8*)&lBh[lk * 520 + co];
      bl4[cf] = *(const bf16x8*)&lBl[lk * 520 + co];
    }
    #pragma unroll
    for (int rf = 0; rf < 2; rf++)
      #pragma unroll
      for (int cf = 0; cf < 4; cf++) {
        acc[rf][cf] = __builtin_amdgcn_mfma_f32_16x16x32_bf16(ah[rf], bh4[cf], acc[rf][cf], 0, 0, 0);
        acc[rf][cf] = __builtin_amdgcn_mfma_f32_16x16x32_bf16(ah[rf], bl4[cf], acc[rf][cf], 0, 0, 0);
        acc[rf][cf] = __builtin_amdgcn_mfma_f32_16x16x32_bf16(al[rf], bh4[cf], acc[rf][cf], 0, 0, 0);
      }
    __syncthreads();
  }

  #pragma unroll
  for (int rf = 0; rf < 2; rf++)
    #pragma unroll
    for (int cf = 0; cf < 4; cf++) {
      const int col = bn + cf * 16 + l15;
      #pragma unroll
      for (int reg = 0; reg < 4; reg++) {
        const int row = bm + wid * 32 + rf * 16 + lk * 4 + reg;
        C[(size_t)row * Ncol + col] = acc[rf][cf][reg];
      }
    }
}

// ---------------------------------------------------------------------------
// Small fp32 GEMM for the N=64 epilogue layers (64x64 tile, 4x4/thread).
// ---------------------------------------------------------------------------
template<int EPI>   // 1 = +bias tanh, 2 = +bias
__global__ __launch_bounds__(256) void gemm_k(
    const float* __restrict__ A, const float* __restrict__ B,
    float* __restrict__ C, const float* __restrict__ bias,
    int M, int Ncol, int K)
{
  __shared__ float As[16][68];
  __shared__ float Bs[16][64];

  const int tid = threadIdx.x;
  const int tx = tid & 15, ty = tid >> 4;
  const int bm = blockIdx.x * 64, bn = blockIdx.y * 64;

  const int arow = tid >> 2;
  const int akc  = (tid & 3) * 4;
  const int brow = tid >> 4;
  const int bc4  = (tid & 15) * 4;

  float acc[4][4];
  #pragma unroll
  for (int i = 0; i < 4; i++)
    #pragma unroll
    for (int j = 0; j < 4; j++) acc[i][j] = 0.f;

  for (int k0 = 0; k0 < K; k0 += 16) {
    const float4 va = *(const float4*)(A + (size_t)(bm + arow) * K + (k0 + akc));
    const float4 vb = *(const float4*)(B + (size_t)(k0 + brow) * Ncol + (bn + bc4));
    As[akc + 0][arow] = va.x; As[akc + 1][arow] = va.y;
    As[akc + 2][arow] = va.z; As[akc + 3][arow] = va.w;
    *(float4*)&Bs[brow][bc4] = vb;
    __syncthreads();
    #pragma unroll
    for (int kk = 0; kk < 16; kk++) {
      const float4 av = *(const float4*)&As[kk][ty * 4];
      const float4 bv = *(const float4*)&Bs[kk][tx * 4];
      const float a4[4] = {av.x, av.y, av.z, av.w};
      const float b4[4] = {bv.x, bv.y, bv.z, bv.w};
      #pragma unroll
      for (int i = 0; i < 4; i++)
        #pragma unroll
        for (int j = 0; j < 4; j++)
          acc[i][j] = fmaf(a4[i], b4[j], acc[i][j]);
    }
    __syncthreads();
  }

  #pragma unroll
  for (int i = 0; i < 4; i++) {
    const int row = bm + ty * 4 + i;
    const int col = bn + tx * 4;
    float v[4] = {acc[i][0], acc[i][1], acc[i][2], acc[i][3]};
    #pragma unroll
    for (int j = 0; j < 4; j++) v[j] += bias[col + j];
    if (EPI == 1) {
      #pragma unroll
      for (int j = 0; j < 4; j++) v[j] = tanhf(v[j]);
    }
    *(float4*)(C + (size_t)row * Ncol + col) = make_float4(v[0], v[1], v[2], v[3]);
  }
}

// ---------------------------------------------------------------------------
// GATv2 aggregation, HC=256 (cout=64): 1 wave per node, 4 nodes/block.
// Lane l owns channels [4l,4l+4); 16-lane group = head. Edges in 4 batches
// of 4; online max-subtracted softmax at batch granularity.
// ---------------------------------------------------------------------------
template<bool CONCAT>
__global__ __launch_bounds__(256) void gat_agg256(
    const float* __restrict__ GL, const float* __restrict__ GR,
    const float* __restrict__ aw_, const float* __restrict__ bias,
    const int* __restrict__ esrc, float* __restrict__ out,
    const float* __restrict__ csrc, int numNodes)
{
  constexpr int HC = 256, C = 64;
  constexpr int OSTR = CONCAT ? 128 : 64;

  const int lane = threadIdx.x & 63;
  const int wid  = threadIdx.x >> 6;
  const int gid  = blockIdx.x * 4 + wid;
  if (gid >= numNodes) return;
  const int t = gid >> 13;
  const int i = gid & (N_ - 1);

  const float* __restrict__ gl = GL + (size_t)t * N_ * HC;
  const int*   __restrict__ es = esrc + (size_t)t * E_ + (size_t)i * DEG_;

  float gr[4], a6[4], a4c[4];
  {
    const float4 gv = *(const float4*)(GR + (size_t)gid * HC + lane * 4);
    const float4 av = *(const float4*)(aw_ + lane * 4);
    gr[0] = gv.x; gr[1] = gv.y; gr[2] = gv.z; gr[3] = gv.w;
    a6[0] = 0.6f * av.x; a6[1] = 0.6f * av.y; a6[2] = 0.6f * av.z; a6[3] = 0.6f * av.w;
    a4c[0] = 0.4f * av.x; a4c[1] = 0.4f * av.y; a4c[2] = 0.4f * av.z; a4c[3] = 0.4f * av.w;
  }

  float acc[4] = {0.f, 0.f, 0.f, 0.f};
  float den = 0.f, m = -1e30f;

  #pragma unroll
  for (int b = 0; b < 4; b++) {
    int js[4];
    #pragma unroll
    for (int q = 0; q < 4; q++) {
      const int ek = b * 4 + q;
      js[q] = (ek < DEG_) ? es[ek] : i;
    }
    float g[4][4];
    #pragma unroll
    for (int q = 0; q < 4; q++) {
      const float4 v = *(const float4*)(gl + (size_t)js[q] * HC + lane * 4);
      g[q][0] = v.x; g[q][1] = v.y; g[q][2] = v.z; g[q][3] = v.w;
    }
    float p[4];
    #pragma unroll
    for (int q = 0; q < 4; q++) {
      float s = 0.f;
      #pragma unroll
      for (int u = 0; u < 4; u++) {
        const float z = g[q][u] + gr[u];
        s = fmaf(z, a6[u], s);
        s = fmaf(fabsf(z), a4c[u], s);
      }
      p[q] = s;
    }
    #pragma unroll
    for (int q = 0; q < 4; q++) {
      p[q] += __shfl_xor(p[q], 1);
      p[q] += __shfl_xor(p[q], 2);
      p[q] += __shfl_xor(p[q], 4);
      p[q] += __shfl_xor(p[q], 8);
    }
    const float bmax = fmaxf(fmaxf(p[0], p[1]), fmaxf(p[2], p[3]));
    const float nm   = fmaxf(m, bmax);
    const float sc   = exp2f((m - nm) * L2E_);
    den *= sc;
    #pragma unroll
    for (int u = 0; u < 4; u++) acc[u] *= sc;
    #pragma unroll
    for (int q = 0; q < 4; q++) {
      const float w = exp2f((p[q] - nm) * L2E_);
      den += w;
      #pragma unroll
      for (int u = 0; u < 4; u++) acc[u] = fmaf(w, g[q][u], acc[u]);
    }
    m = nm;
  }

  const float inv = 1.f / den;
  #pragma unroll
  for (int u = 0; u < 4; u++) acc[u] *= inv;
  #pragma unroll
  for (int u = 0; u < 4; u++) {
    acc[u] += __shfl_xor(acc[u], 16);
    acc[u] += __shfl_xor(acc[u], 32);
  }

  float* orow = out + (size_t)gid * OSTR;
  if (lane < 16) {
    #pragma unroll
    for (int u = 0; u < 4; u++)
      acc[u] = elu1(acc[u] * 0.25f + bias[lane * 4 + u]);
    *(float4*)(orow + lane * 4) = make_float4(acc[0], acc[1], acc[2], acc[3]);
  } else if (CONCAT && lane < 32) {
    const int q = lane - 16;
    const float4 v = *(const float4*)(csrc + (size_t)gid * C + q * 4);
    *(float4*)(orow + C + q * 4) =
        make_float4(elu1(v.x), elu1(v.y), elu1(v.z), elu1(v.w));
  }
}

// ---------------------------------------------------------------------------
// GATv2 aggregation, HC=512 (cout=128): 1 node per block, 1 head per wave.
// NEW: wave split into 4 edge-groups x 16 sublanes; sublane owns 8 channels
// (16 lanes cover the head's 128 ch); group g handles edges [4g,4g+4).
// Score reduce = 4 shfl over 16 lanes, 4 edges in parallel (16 shfl total vs
// 96). Shared max M across groups (xor16/32) = exact per-head segment max.
// Message phase reloads g (L1/L2-hot) to keep VGPR ~60.
// ---------------------------------------------------------------------------
__global__ __launch_bounds__(256) void gat_agg512(
    const float* __restrict__ GL, const float* __restrict__ GR,
    const float* __restrict__ aw_, const float* __restrict__ bias,
    const int* __restrict__ esrc, float* __restrict__ out)
{
  __shared__ float smem[4][128];

  const int lane = threadIdx.x & 63;
  const int h    = threadIdx.x >> 6;
  const int gid  = blockIdx.x;
  const int t = gid >> 13;
  const int i = gid & (N_ - 1);

  const float* __restrict__ gl = GL + (size_t)t * N_ * 512;
  const int*   __restrict__ es = esrc + (size_t)t * E_ + (size_t)i * DEG_;

  const int grp = lane >> 4;        // edge group
  const int s   = lane & 15;        // sublane: channels [8s, 8s+8) of head
  const int cb  = h * 128 + s * 8;  // channel base within 512-row

  float gr[8], a6[8], a4[8];
  {
    const float4 g0 = *(const float4*)(GR + (size_t)gid * 512 + cb);
    const float4 g1 = *(const float4*)(GR + (size_t)gid * 512 + cb + 4);
    gr[0] = g0.x; gr[1] = g0.y; gr[2] = g0.z; gr[3] = g0.w;
    gr[4] = g1.x; gr[5] = g1.y; gr[6] = g1.z; gr[7] = g1.w;
    const float4 a0 = *(const float4*)(aw_ + cb);
    const float4 a1 = *(const float4*)(aw_ + cb + 4);
    a6[0] = 0.6f * a0.x; a6[1] = 0.6f * a0.y; a6[2] = 0.6f * a0.z; a6[3] = 0.6f * a0.w;
    a6[4] = 0.6f * a1.x; a6[5] = 0.6f * a1.y; a6[6] = 0.6f * a1.z; a6[7] = 0.6f * a1.w;
    a4[0] = 0.4f * a0.x; a4[1] = 0.4f * a0.y; a4[2] = 0.4f * a0.z; a4[3] = 0.4f * a0.w;
    a4[4] = 0.4f * a1.x; a4[5] = 0.4f * a1.y; a4[6] = 0.4f * a1.z; a4[7] = 0.4f * a1.w;
  }

  int js[4];
  #pragma unroll
  for (int q = 0; q < 4; q++) {
    const int ek = grp * 4 + q;
    js[q] = (ek < DEG_) ? es[ek] : i;
  }

  // ---- score phase: 2 sub-batches of 2 edges (transient g regs) ----
  float p[4];
  #pragma unroll
  for (int b = 0; b < 2; b++) {
    float gq[2][8];
    #pragma unroll
    for (int q = 0; q < 2; q++) {
      const float* gp = gl + (size_t)js[b * 2 + q] * 512 + cb;
      const float4 v0 = *(const float4*)gp;
      const float4 v1 = *(const float4*)(gp + 4);
      gq[q][0] = v0.x; gq[q][1] = v0.y; gq[q][2] = v0.z; gq[q][3] = v0.w;
      gq[q][4] = v1.x; gq[q][5] = v1.y; gq[q][6] = v1.z; gq[q][7] = v1.w;
    }
    #pragma unroll
    for (int q = 0; q < 2; q++) {
      float sc = 0.f;
      #pragma unroll
      for (int u = 0; u < 8; u++) {
        const float z = gq[q][u] + gr[u];
        sc = fmaf(z, a6[u], sc);
        sc = fmaf(fabsf(z), a4[u], sc);
      }
      p[b * 2 + q] = sc;
    }
  }
  // 16-lane reduce per score (4 edges in parallel across groups)
  #pragma unroll
  for (int q = 0; q < 4; q++) {
    p[q] += __shfl_xor(p[q], 1);
    p[q] += __shfl_xor(p[q], 2);
    p[q] += __shfl_xor(p[q], 4);
    p[q] += __shfl_xor(p[q], 8);
  }
  // head-wide max across the 4 groups
  float M = fmaxf(fmaxf(p[0], p[1]), fmaxf(p[2], p[3]));
  M = fmaxf(M, __shfl_xor(M, 16));
  M = fmaxf(M, __shfl_xor(M, 32));

  float w[4];
  float den = 0.f;
  #pragma unroll
  for (int q = 0; q < 4; q++) { w[q] = exp2f((p[q] - M) * L2E_); den += w[q]; }

  // ---- message phase: reload g (L1/L2-hot), weighted sum ----
  float acc[8] = {0.f, 0.f, 0.f, 0.f, 0.f, 0.f, 0.f, 0.f};
  #pragma unroll
  for (int b = 0; b < 2; b++) {
    float gq[2][8];
    #pragma unroll
    for (int q = 0; q < 2; q++) {
      const float* gp = gl + (size_t)js[b * 2 + q] * 512 + cb;
      const float4 v0 = *(const float4*)gp;
      const float4 v1 = *(const float4*)(gp + 4);
      gq[q][0] = v0.x; gq[q][1] = v0.y; gq[q][2] = v0.z; gq[q][3] = v0.w;
      gq[q][4] = v1.x; gq[q][5] = v1.y; gq[q][6] = v1.z; gq[q][7] = v1.w;
    }
    #pragma unroll
    for (int q = 0; q < 2; q++)
      #pragma unroll
      for (int u = 0; u < 8; u++)
        acc[u] = fmaf(w[b * 2 + q], gq[q][u], acc[u]);
  }

  // cross-group combine (same channels live on lanes s, s+16, s+32, s+48)
  den += __shfl_xor(den, 16);
  den += __shfl_xor(den, 32);
  #pragma unroll
  for (int u = 0; u < 8; u++) {
    acc[u] += __shfl_xor(acc[u], 16);
    acc[u] += __shfl_xor(acc[u], 32);
  }

  const float inv = 1.f / den;
  if (grp == 0) {
    float o[8];
    #pragma unroll
    for (int u = 0; u < 8; u++) o[u] = acc[u] * inv;
    *(float4*)&smem[h][s * 8]     = make_float4(o[0], o[1], o[2], o[3]);
    *(float4*)&smem[h][s * 8 + 4] = make_float4(o[4], o[5], o[6], o[7]);
  }
  __syncthreads();

  if (h == 0) {
    const int c = lane * 2;
    float s0 = smem[0][c] + smem[1][c] + smem[2][c] + smem[3][c];
    float s1 = smem[0][c + 1] + smem[1][c + 1] + smem[2][c + 1] + smem[3][c + 1];
    s0 = elu1(s0 * 0.25f + bias[c]);
    s1 = elu1(s1 * 0.25f + bias[c + 1]);
    *(float2*)(out + (size_t)gid * 128 + c) = make_float2(s0, s1);
  }
}

// ---------------------------------------------------------------------------
extern "C" void kernel_launch(void* const* d_in, const int* in_sizes, int n_in,
                              void* d_out, int out_size, void* d_ws, size_t ws_size,
                              hipStream_t stream)
{
  (void)in_sizes; (void)n_in; (void)out_size; (void)ws_size;

  const float* x  = (const float*)d_in[0];
  const int*   es = (const int*)d_in[1];
  const float *c1_wl=(const float*)d_in[3], *c1_wr=(const float*)d_in[4], *c1_a=(const float*)d_in[5], *c1_b=(const float*)d_in[6];
  const float *c2_wl=(const float*)d_in[7], *c2_wr=(const float*)d_in[8], *c2_a=(const float*)d_in[9], *c2_b=(const float*)d_in[10];
  const float *c3_wl=(const float*)d_in[11],*c3_wr=(const float*)d_in[12],*c3_a=(const float*)d_in[13],*c3_b=(const float*)d_in[14];
  const float *c4_wl=(const float*)d_in[15],*c4_wr=(const float*)d_in[16],*c4_a=(const float*)d_in[17],*c4_b=(const float*)d_in[18];
  const float *r11_wl=(const float*)d_in[19],*r11_wr=(const float*)d_in[20],*r11_a=(const float*)d_in[21],*r11_b=(const float*)d_in[22];
  const float *r12_wl=(const float*)d_in[23],*r12_wr=(const float*)d_in[24],*r12_a=(const float*)d_in[25],*r12_b=(const float*)d_in[26];
  const float *r2_wl=(const float*)d_in[27],*r2_wr=(const float*)d_in[28],*r2_a=(const float*)d_in[29],*r2_b=(const float*)d_in[30];
  const float *f11_wl=(const float*)d_in[31],*f11_wr=(const float*)d_in[32],*f11_a=(const float*)d_in[33],*f11_b=(const float*)d_in[34];
  const float *f2_wl=(const float*)d_in[35],*f2_wr=(const float*)d_in[36],*f2_a=(const float*)d_in[37],*f2_b=(const float*)d_in[38];
  const float *r3_w=(const float*)d_in[39], *r3_b=(const float*)d_in[40];
  const float *f3_w=(const float*)d_in[41], *f3_b=(const float*)d_in[42];
  const float *r4_w=(const float*)d_in[43], *r4_b=(const float*)d_in[44];
  const float *f4_w=(const float*)d_in[45], *f4_b=(const float*)d_in[46];

  float* ws = (float*)d_ws;
  float* GL = ws;
  float* GR = GL + (size_t)16777216;
  float* A0 = GR + (size_t)16777216;            // [T,N,128]
  float* A1 = A0 + (size_t)T_ * N_ * 128;       // [T,N,64]
  float* B0 = A1 + (size_t)T_ * N_ * 64;        // [N,128]
  float* B1 = B0 + (size_t)N_ * 128;            // [N,128]
  ushort* SH = (ushort*)(B1 + (size_t)N_ * 128);        // split A hi (max T*N*128)
  ushort* SL = SH + (size_t)8388608;                    // split A lo
  ushort* WH = SL + (size_t)8388608;                    // split W hi [2][HC][K]
  ushort* WL = WH + (size_t)131072;                     // split W lo

  float* recon = (float*)d_out;
  float* fcst  = recon + (size_t)N_ * 64;
  float* emb   = fcst + (size_t)N_ * 64;        // [T,N,64]

  const dim3 blk(256);

  // ---- c1: 64 -> 128 (HC=512), 2 GEMM chunks of 4 timesteps ----
  split_x<<<dim3((T_ * N_ * 64 / 4 + 255) / 256), blk, 0, stream>>>(x, SH, SL, T_ * N_ * 64 / 4);
  split_wt<<<dim3((2 * 512 * 64 + 255) / 256), blk, 0, stream>>>(c1_wl, c1_wr, WH, WL, 64, 512);
  for (int ch = 0; ch < 2; ch++) {
    const int t0 = ch * 4, nt = 4;
    gemm_mfma<<<dim3(N_ / 128, 8, 2 * nt), blk, 0, stream>>>(
        SH + (size_t)t0 * N_ * 64, SL + (size_t)t0 * N_ * 64, WH, WL, GL, GR, N_, 512, 64, nt);
    gat_agg512<<<dim3(nt * N_), blk, 0, stream>>>(
        GL, GR, c1_a, c1_b, es + (size_t)t0 * E_, A0 + (size_t)t0 * N_ * 128);
  }
  // ---- c2: 128 -> 64 (HC=256) ----
  split_x<<<dim3((T_ * N_ * 128 / 4 + 255) / 256), blk, 0, stream>>>(A0, SH, SL, T_ * N_ * 128 / 4);
  split_wt<<<dim3((2 * 256 * 128 + 255) / 256), blk, 0, stream>>>(c2_wl, c2_wr, WH, WL, 128, 256);
  gemm_mfma<<<dim3(N_ / 128, 4, 2 * T_), blk, 0, stream>>>(SH, SL, WH, WL, GL, GR, N_, 256, 128, T_);
  gat_agg256<false><<<dim3(T_ * N_ / 4), blk, 0, stream>>>(GL, GR, c2_a, c2_b, es, A1, nullptr, T_ * N_);
  // ---- c3: 64 -> 64 (HC=256), concat with elu(emb2) ----
  split_x<<<dim3((T_ * N_ * 64 / 4 + 255) / 256), blk, 0, stream>>>(A1, SH, SL, T_ * N_ * 64 / 4);
  split_wt<<<dim3((2 * 256 * 64 + 255) / 256), blk, 0, stream>>>(c3_wl, c3_wr, WH, WL, 64, 256);
  gemm_mfma<<<dim3(N_ / 128, 4, 2 * T_), blk, 0, stream>>>(SH, SL, WH, WL, GL, GR, N_, 256, 64, T_);
  gat_agg256<true><<<dim3(T_ * N_ / 4), blk, 0, stream>>>(GL, GR, c3_a, c3_b, es, A0, A1, T_ * N_);
  // ---- c4: 128 -> 64 (HC=256) -> emb ----
  split_x<<<dim3((T_ * N_ * 128 / 4 + 255) / 256), blk, 0, stream>>>(A0, SH, SL, T_ * N_ * 128 / 4);
  split_wt<<<dim3((2 * 256 * 128 + 255) / 256), blk, 0, stream>>>(c4_wl, c4_wr, WH, WL, 128, 256);
  gemm_mfma<<<dim3(N_ / 128, 4, 2 * T_), blk, 0, stream>>>(SH, SL, WH, WL, GL, GR, N_, 256, 128, T_);
  gat_agg256<false><<<dim3(T_ * N_ / 4), blk, 0, stream>>>(GL, GR, c4_a, c4_b, es, emb, nullptr, T_ * N_);

  // ---- reconstruction branch (edges at t = 7) ----
  const float* embR = emb + (size_t)7 * N_ * 64;
  const int*   esR  = es + (size_t)7 * E_;
  split_x<<<dim3((N_ * 64 / 4 + 255) / 256), blk, 0, stream>>>(embR, SH, SL, N_ * 64 / 4);
  split_wt<<<dim3((2 * 256 * 64 + 255) / 256), blk, 0, stream>>>(r11_wl, r11_wr, WH, WL, 64, 256);
  gemm_mfma<<<dim3(N_ / 128, 4, 2), blk, 0, stream>>>(SH, SL, WH, WL, GL, GR, N_, 256, 64, 1);
  gat_agg256<false><<<dim3(N_ / 4), blk, 0, stream>>>(GL, GR, r11_a, r11_b, esR, B0, nullptr, N_);
  split_x<<<dim3((N_ * 64 / 4 + 255) / 256), blk, 0, stream>>>(B0, SH, SL, N_ * 64 / 4);
  split_wt<<<dim3((2 * 256 * 64 + 255) / 256), blk, 0, stream>>>(r12_wl, r12_wr, WH, WL, 64, 256);
  gemm_mfma<<<dim3(N_ / 128, 4, 2), blk, 0, stream>>>(SH, SL, WH, WL, GL, GR, N_, 256, 64, 1);
  gat_agg256<true><<<dim3(N_ / 4), blk, 0, stream>>>(GL, GR, r12_a, r12_b, esR, B1, B0, N_);
  split_x<<<dim3((N_ * 128 / 4 + 255) / 256), blk, 0, stream>>>(B1, SH, SL, N_ * 128 / 4);
  split_wt<<<dim3((2 * 512 * 128 + 255) / 256), blk, 0, stream>>>(r2_wl, r2_wr, WH, WL, 128, 512);
  gemm_mfma<<<dim3(N_ / 128, 8, 2), blk, 0, stream>>>(SH, SL, WH, WL, GL, GR, N_, 512, 128, 1);
  gat_agg512<<<dim3(N_), blk, 0, stream>>>(GL, GR, r2_a, r2_b, esR, B0);
  gemm_k<1><<<dim3(N_ / 64, 1, 1), blk, 0, stream>>>(B0, r3_w, B1, r3_b, N_, 64, 128);
  gemm_k<2><<<dim3(N_ / 64, 1, 1), blk, 0, stream>>>(B1, r4_w, recon, r4_b, N_, 64, 64);

  // ---- forecasting branch (edges at t = 6; concat layer reuses r12 weights) ----
  const float* embF = emb + (size_t)6 * N_ * 64;
  const int*   esF  = es + (size_t)6 * E_;
  split_x<<<dim3((N_ * 64 / 4 + 255) / 256), blk, 0, stream>>>(embF, SH, SL, N_ * 64 / 4);
  split_wt<<<dim3((2 * 256 * 64 + 255) / 256), blk, 0, stream>>>(f11_wl, f11_wr, WH, WL, 64, 256);
  gemm_mfma<<<dim3(N_ / 128, 4, 2), blk, 0, stream>>>(SH, SL, WH, WL, GL, GR, N_, 256, 64, 1);
  gat_agg256<false><<<dim3(N_ / 4), blk, 0, stream>>>(GL, GR, f11_a, f11_b, esF, B0, nullptr, N_);
  split_x<<<dim3((N_ * 64 / 4 + 255) / 256), blk, 0, stream>>>(B0, SH, SL, N_ * 64 / 4);
  split_wt<<<dim3((2 * 256 * 64 + 255) / 256), blk, 0, stream>>>(r12_wl, r12_wr, WH, WL, 64, 256);
  gemm_mfma<<<dim3(N_ / 128, 4, 2), blk, 0, stream>>>(SH, SL, WH, WL, GL, GR, N_, 256, 64, 1);
  gat_agg256<true><<<dim3(N_ / 4), blk, 0, stream>>>(GL, GR, r12_a, r12_b, esF, B1, B0, N_);
  split_x<<<dim3((N_ * 128 / 4 + 255) / 256), blk, 0, stream>>>(B1, SH, SL, N_ * 128 / 4);
  split_wt<<<dim3((2 * 512 * 128 + 255) / 256), blk, 0, stream>>>(f2_wl, f2_wr, WH, WL, 128, 512);
  gemm_mfma<<<dim3(N_ / 128, 8, 2), blk, 0, stream>>>(SH, SL, WH, WL, GL, GR, N_, 512, 128, 1);
  gat_agg512<<<dim3(N_), blk, 0, stream>>>(GL, GR, f2_a, f2_b, esF, B0);
  gemm_k<1><<<dim3(N_ / 64, 1, 1), blk, 0, stream>>>(B0, f3_w, B1, f3_b, N_, 64, 128);
  gemm_k<2><<<dim3(N_ / 64, 1, 1), blk, 0, stream>>>(B1, f4_w, fcst, f4_b, N_, 64, 64);
}

// Round 8
// 1036.422 us; speedup vs baseline: 1.3584x; 1.3584x over previous
//
#include <hip/hip_runtime.h>
#include <cmath>

// Problem constants (from reference setup_inputs)
constexpr int T_   = 8;
constexpr int N_   = 8192;
constexpr int DEG_ = 15;
constexpr int E_   = N_ * (DEG_ + 1);   // 131072 edges per timestep
constexpr float L2E_ = 1.44269504f;

__device__ __forceinline__ float elu1(float v) { return v > 0.f ? v : expm1f(v); }

typedef __attribute__((ext_vector_type(8))) short bf16x8;
typedef __attribute__((ext_vector_type(4))) float f32x4;

__device__ __forceinline__ ushort f2bf(float x) {
  uint u = __float_as_uint(x);
  return (ushort)((u + 0x7FFFu + ((u >> 16) & 1u)) >> 16);
}
__device__ __forceinline__ float bf2f(ushort h) {
  return __uint_as_float(((uint)h) << 16);
}

// v_add with DPP row_ror: sum over each 16-lane row after steps 1,2,4,8.
template<int CTRL>
__device__ __forceinline__ float dpp_add(float x) {
  const int t = __builtin_amdgcn_mov_dpp(__float_as_int(x), CTRL, 0xf, 0xf, true);
  return x + __int_as_float(t);
}
__device__ __forceinline__ float row_reduce16(float x) {
  x = dpp_add<0x121>(x);   // row_ror:1
  x = dpp_add<0x122>(x);   // row_ror:2
  x = dpp_add<0x124>(x);   // row_ror:4
  x = dpp_add<0x128>(x);   // row_ror:8
  return x;                // all 16 lanes of the row hold the row sum
}

// ---------------------------------------------------------------------------
// split_x: fp32 array -> hi/lo bf16 arrays (same layout). 4 elems/thread.
// ---------------------------------------------------------------------------
__global__ __launch_bounds__(256) void split_x(
    const float* __restrict__ X, ushort* __restrict__ XH, ushort* __restrict__ XL, int n4)
{
  const int i = blockIdx.x * 256 + threadIdx.x;
  if (i >= n4) return;
  const float4 v = ((const float4*)X)[i];
  const ushort h0 = f2bf(v.x), h1 = f2bf(v.y), h2 = f2bf(v.z), h3 = f2bf(v.w);
  ushort4 hh; hh.x = h0; hh.y = h1; hh.z = h2; hh.w = h3;
  ushort4 ll;
  ll.x = f2bf(v.x - bf2f(h0)); ll.y = f2bf(v.y - bf2f(h1));
  ll.z = f2bf(v.z - bf2f(h2)); ll.w = f2bf(v.w - bf2f(h3));
  ((ushort4*)XH)[i] = hh;
  ((ushort4*)XL)[i] = ll;
}

// ---------------------------------------------------------------------------
// split_wt: W_l, W_r [K, HC] fp32 -> WH/WL [2][HC][K] bf16 (transposed).
// ---------------------------------------------------------------------------
__global__ __launch_bounds__(256) void split_wt(
    const float* __restrict__ Wl, const float* __restrict__ Wr,
    ushort* __restrict__ WH, ushort* __restrict__ WL, int K, int HC)
{
  const int idx = blockIdx.x * 256 + threadIdx.x;
  if (idx >= 2 * HC * K) return;
  const int k = idx % K;
  const int n = (idx / K) % HC;
  const int s = idx / (K * HC);
  const float v = (s ? Wr : Wl)[k * HC + n];
  const ushort h = f2bf(v);
  WH[idx] = h;
  WL[idx] = f2bf(v - bf2f(h));
}

// ---------------------------------------------------------------------------
// MFMA GEMM (split-bf16): C = A @ W, A hi/lo [nt][M][K] bf16, W hi/lo
// [2][Ncol][K] bf16 (transposed). x.w ~= ah.wh + ah.wl + al.wh.
// BM=128, BN=64, BK=32; 256 thr = 4 waves.
// ---------------------------------------------------------------------------
__global__ __launch_bounds__(256) void gemm_mfma(
    const ushort* __restrict__ Ah, const ushort* __restrict__ Al,
    const ushort* __restrict__ Wh, const ushort* __restrict__ Wl,
    float* __restrict__ Cl, float* __restrict__ Cr,
    int M, int Ncol, int K, int nt)
{
  __shared__ alignas(16) ushort lAh[4 * 1032];
  __shared__ alignas(16) ushort lAl[4 * 1032];
  __shared__ alignas(16) ushort lBh[4 * 520];
  __shared__ alignas(16) ushort lBl[4 * 520];

  const int z = blockIdx.z;
  const int t = (z < nt) ? z : z - nt;
  const int side = (z < nt) ? 0 : 1;
  const ushort* __restrict__ Bh = Wh + (size_t)side * Ncol * K;
  const ushort* __restrict__ Bl = Wl + (size_t)side * Ncol * K;
  float* __restrict__ C = (side ? Cr : Cl) + (size_t)t * M * Ncol;
  const size_t aoff = (size_t)t * M * K;

  const int bm = blockIdx.x * 128, bn = blockIdx.y * 64;
  const int tid = threadIdx.x;
  const int wid = tid >> 6, lane = tid & 63;
  const int l15 = lane & 15, lk = lane >> 4;

  f32x4 acc[2][4] = {};

  for (int k0 = 0; k0 < K; k0 += 32) {
    #pragma unroll
    for (int c = 0; c < 2; c++) {
      const int ch = tid + c * 256;
      const int row = ch >> 2, kc = ch & 3;
      const size_t ga = aoff + (size_t)(bm + row) * K + (k0 + kc * 8);
      *(uint4*)&lAh[kc * 1032 + row * 8] = *(const uint4*)(Ah + ga);
      *(uint4*)&lAl[kc * 1032 + row * 8] = *(const uint4*)(Al + ga);
    }
    {
      const int col = tid >> 2, kc = tid & 3;
      const size_t gb = (size_t)(bn + col) * K + (k0 + kc * 8);
      *(uint4*)&lBh[kc * 520 + col * 8] = *(const uint4*)(Bh + gb);
      *(uint4*)&lBl[kc * 520 + col * 8] = *(const uint4*)(Bl + gb);
    }
    __syncthreads();

    bf16x8 ah[2], al[2], bh4[4], bl4[4];
    const int r0 = wid * 32;
    #pragma unroll
    for (int rf = 0; rf < 2; rf++) {
      const int ro = (r0 + rf * 16 + l15) * 8;
      ah[rf] = *(const bf16x8*)&lAh[lk * 1032 + ro];
      al[rf] = *(const bf16x8*)&lAl[lk * 1032 + ro];
    }
    #pragma unroll
    for (int cf = 0; cf < 4; cf++) {
      const int co = (cf * 16 + l15) * 8;
      bh4[cf] = *(const bf16x8*)&lBh[lk * 520 + co];
      bl4[cf] = *(const bf16x8*)&lBl[lk * 520 + co];
    }
    #pragma unroll
    for (int rf = 0; rf < 2; rf++)
      #pragma unroll
      for (int cf = 0; cf < 4; cf++) {
        acc[rf][cf] = __builtin_amdgcn_mfma_f32_16x16x32_bf16(ah[rf], bh4[cf], acc[rf][cf], 0, 0, 0);
        acc[rf][cf] = __builtin_amdgcn_mfma_f32_16x16x32_bf16(ah[rf], bl4[cf], acc[rf][cf], 0, 0, 0);
        acc[rf][cf] = __builtin_amdgcn_mfma_f32_16x16x32_bf16(al[rf], bh4[cf], acc[rf][cf], 0, 0, 0);
      }
    __syncthreads();
  }

  #pragma unroll
  for (int rf = 0; rf < 2; rf++)
    #pragma unroll
    for (int cf = 0; cf < 4; cf++) {
      const int col = bn + cf * 16 + l15;
      #pragma unroll
      for (int reg = 0; reg < 4; reg++) {
        const int row = bm + wid * 32 + rf * 16 + lk * 4 + reg;
        C[(size_t)row * Ncol + col] = acc[rf][cf][reg];
      }
    }
}

// ---------------------------------------------------------------------------
// Small fp32 GEMM for the N=64 epilogue layers (64x64 tile, 4x4/thread).
// ---------------------------------------------------------------------------
template<int EPI>   // 1 = +bias tanh, 2 = +bias
__global__ __launch_bounds__(256) void gemm_k(
    const float* __restrict__ A, const float* __restrict__ B,
    float* __restrict__ C, const float* __restrict__ bias,
    int M, int Ncol, int K)
{
  __shared__ float As[16][68];
  __shared__ float Bs[16][64];

  const int tid = threadIdx.x;
  const int tx = tid & 15, ty = tid >> 4;
  const int bm = blockIdx.x * 64, bn = blockIdx.y * 64;

  const int arow = tid >> 2;
  const int akc  = (tid & 3) * 4;
  const int brow = tid >> 4;
  const int bc4  = (tid & 15) * 4;

  float acc[4][4];
  #pragma unroll
  for (int i = 0; i < 4; i++)
    #pragma unroll
    for (int j = 0; j < 4; j++) acc[i][j] = 0.f;

  for (int k0 = 0; k0 < K; k0 += 16) {
    const float4 va = *(const float4*)(A + (size_t)(bm + arow) * K + (k0 + akc));
    const float4 vb = *(const float4*)(B + (size_t)(k0 + brow) * Ncol + (bn + bc4));
    As[akc + 0][arow] = va.x; As[akc + 1][arow] = va.y;
    As[akc + 2][arow] = va.z; As[akc + 3][arow] = va.w;
    *(float4*)&Bs[brow][bc4] = vb;
    __syncthreads();
    #pragma unroll
    for (int kk = 0; kk < 16; kk++) {
      const float4 av = *(const float4*)&As[kk][ty * 4];
      const float4 bv = *(const float4*)&Bs[kk][tx * 4];
      const float a4[4] = {av.x, av.y, av.z, av.w};
      const float b4[4] = {bv.x, bv.y, bv.z, bv.w};
      #pragma unroll
      for (int i = 0; i < 4; i++)
        #pragma unroll
        for (int j = 0; j < 4; j++)
          acc[i][j] = fmaf(a4[i], b4[j], acc[i][j]);
    }
    __syncthreads();
  }

  #pragma unroll
  for (int i = 0; i < 4; i++) {
    const int row = bm + ty * 4 + i;
    const int col = bn + tx * 4;
    float v[4] = {acc[i][0], acc[i][1], acc[i][2], acc[i][3]};
    #pragma unroll
    for (int j = 0; j < 4; j++) v[j] += bias[col + j];
    if (EPI == 1) {
      #pragma unroll
      for (int j = 0; j < 4; j++) v[j] = tanhf(v[j]);
    }
    *(float4*)(C + (size_t)row * Ncol + col) = make_float4(v[0], v[1], v[2], v[3]);
  }
}

// ---------------------------------------------------------------------------
// GATv2 aggregation, HC=256 (cout=64): 1 wave per node, 4 nodes/block.
// Lane l owns channels [4l,4l+4); 16-lane group = head. Edges in 4 batches
// of 4; online max-subtracted softmax at batch granularity (scores in log2
// domain: 0.6*L2E / 0.4*L2E baked into attention weights).
// Optional fused bf16 hi/lo split of the output row (SHo/SLo non-null).
// ---------------------------------------------------------------------------
template<bool CONCAT>
__global__ __launch_bounds__(256) void gat_agg256(
    const float* __restrict__ GL, const float* __restrict__ GR,
    const float* __restrict__ aw_, const float* __restrict__ bias,
    const int* __restrict__ esrc, float* __restrict__ out,
    const float* __restrict__ csrc,
    ushort* __restrict__ SHo, ushort* __restrict__ SLo, int numNodes)
{
  constexpr int HC = 256, C = 64;
  constexpr int OSTR = CONCAT ? 128 : 64;

  const int lane = threadIdx.x & 63;
  const int wid  = threadIdx.x >> 6;
  const int gid  = blockIdx.x * 4 + wid;
  if (gid >= numNodes) return;
  const int t = gid >> 13;
  const int i = gid & (N_ - 1);

  const float* __restrict__ gl = GL + (size_t)t * N_ * HC;
  const int*   __restrict__ es = esrc + (size_t)t * E_ + (size_t)i * DEG_;

  float gr[4], a6[4], a4c[4];
  {
    const float4 gv = *(const float4*)(GR + (size_t)gid * HC + lane * 4);
    const float4 av = *(const float4*)(aw_ + lane * 4);
    gr[0] = gv.x; gr[1] = gv.y; gr[2] = gv.z; gr[3] = gv.w;
    a6[0] = 0.6f * L2E_ * av.x; a6[1] = 0.6f * L2E_ * av.y;
    a6[2] = 0.6f * L2E_ * av.z; a6[3] = 0.6f * L2E_ * av.w;
    a4c[0] = 0.4f * L2E_ * av.x; a4c[1] = 0.4f * L2E_ * av.y;
    a4c[2] = 0.4f * L2E_ * av.z; a4c[3] = 0.4f * L2E_ * av.w;
  }

  float acc[4] = {0.f, 0.f, 0.f, 0.f};
  float den = 0.f, m = -1e30f;

  #pragma unroll
  for (int b = 0; b < 4; b++) {
    int js[4];
    #pragma unroll
    for (int q = 0; q < 4; q++) {
      const int ek = b * 4 + q;
      js[q] = (ek < DEG_) ? es[ek] : i;
    }
    float g[4][4];
    #pragma unroll
    for (int q = 0; q < 4; q++) {
      const float4 v = *(const float4*)(gl + (size_t)js[q] * HC + lane * 4);
      g[q][0] = v.x; g[q][1] = v.y; g[q][2] = v.z; g[q][3] = v.w;
    }
    float p[4];
    #pragma unroll
    for (int q = 0; q < 4; q++) {
      float s = 0.f;
      #pragma unroll
      for (int u = 0; u < 4; u++) {
        const float z = g[q][u] + gr[u];
        s = fmaf(z, a6[u], s);
        s = fmaf(fabsf(z), a4c[u], s);
      }
      p[q] = s;
    }
    // reduce within 16-lane head group (DPP rotate-reduce, VALU pipe)
    #pragma unroll
    for (int q = 0; q < 4; q++) p[q] = row_reduce16(p[q]);

    const float bmax = fmaxf(fmaxf(p[0], p[1]), fmaxf(p[2], p[3]));
    const float nm   = fmaxf(m, bmax);
    const float sc   = exp2f(m - nm);     // 0 on first batch
    den *= sc;
    #pragma unroll
    for (int u = 0; u < 4; u++) acc[u] *= sc;
    #pragma unroll
    for (int q = 0; q < 4; q++) {
      const float w = exp2f(p[q] - nm);
      den += w;
      #pragma unroll
      for (int u = 0; u < 4; u++) acc[u] = fmaf(w, g[q][u], acc[u]);
    }
    m = nm;
  }

  const float inv = 0.25f / den;          // per-head normalizer * head-mean
  #pragma unroll
  for (int u = 0; u < 4; u++) acc[u] *= inv;
  #pragma unroll
  for (int u = 0; u < 4; u++) {
    acc[u] += __shfl_xor(acc[u], 16);
    acc[u] += __shfl_xor(acc[u], 32);
  }

  float* orow = out + (size_t)gid * OSTR;
  if (lane < 16) {
    float o[4];
    #pragma unroll
    for (int u = 0; u < 4; u++)
      o[u] = elu1(acc[u] + bias[lane * 4 + u]);
    *(float4*)(orow + lane * 4) = make_float4(o[0], o[1], o[2], o[3]);
    if (SHo) {
      ushort4 hh, ll;
      hh.x = f2bf(o[0]); hh.y = f2bf(o[1]); hh.z = f2bf(o[2]); hh.w = f2bf(o[3]);
      ll.x = f2bf(o[0] - bf2f(hh.x)); ll.y = f2bf(o[1] - bf2f(hh.y));
      ll.z = f2bf(o[2] - bf2f(hh.z)); ll.w = f2bf(o[3] - bf2f(hh.w));
      *(ushort4*)(SHo + (size_t)gid * OSTR + lane * 4) = hh;
      *(ushort4*)(SLo + (size_t)gid * OSTR + lane * 4) = ll;
    }
  } else if (CONCAT && lane < 32) {
    const int q = lane - 16;
    const float4 v = *(const float4*)(csrc + (size_t)gid * C + q * 4);
    const float o0 = elu1(v.x), o1 = elu1(v.y), o2 = elu1(v.z), o3 = elu1(v.w);
    *(float4*)(orow + C + q * 4) = make_float4(o0, o1, o2, o3);
    if (SHo) {
      ushort4 hh, ll;
      hh.x = f2bf(o0); hh.y = f2bf(o1); hh.z = f2bf(o2); hh.w = f2bf(o3);
      ll.x = f2bf(o0 - bf2f(hh.x)); ll.y = f2bf(o1 - bf2f(hh.y));
      ll.z = f2bf(o2 - bf2f(hh.z)); ll.w = f2bf(o3 - bf2f(hh.w));
      *(ushort4*)(SHo + (size_t)gid * OSTR + C + q * 4) = hh;
      *(ushort4*)(SLo + (size_t)gid * OSTR + C + q * 4) = ll;
    }
  }
}

// ---------------------------------------------------------------------------
// GATv2 aggregation, HC=512 (cout=128): 1 node per block, 1 head per wave.
// Lane l owns channels [2l,2l+2) (r5 structure: batched loads, online batch
// softmax, no load-behind-reduce). Scores in log2 domain (L2E baked).
// Reduce: DPP rows + shfl 16/32.
// ---------------------------------------------------------------------------
__global__ __launch_bounds__(256) void gat_agg512(
    const float* __restrict__ GL, const float* __restrict__ GR,
    const float* __restrict__ aw_, const float* __restrict__ bias,
    const int* __restrict__ esrc, float* __restrict__ out)
{
  __shared__ float smem[4][128];

  const int lane = threadIdx.x & 63;
  const int h    = threadIdx.x >> 6;
  const int gid  = blockIdx.x;
  const int t = gid >> 13;
  const int i = gid & (N_ - 1);

  const float* __restrict__ gl = GL + (size_t)t * N_ * 512;
  const int*   __restrict__ es = esrc + (size_t)t * E_ + (size_t)i * DEG_;
  const int cb = h * 128 + lane * 2;

  float gr0, gr1, a60, a61, a40, a41;
  {
    const float2 gv = *(const float2*)(GR + (size_t)gid * 512 + cb);
    const float2 av = *(const float2*)(aw_ + cb);
    gr0 = gv.x; gr1 = gv.y;
    a60 = 0.6f * L2E_ * av.x; a61 = 0.6f * L2E_ * av.y;
    a40 = 0.4f * L2E_ * av.x; a41 = 0.4f * L2E_ * av.y;
  }

  float acc0 = 0.f, acc1 = 0.f, den = 0.f, m = -1e30f;

  #pragma unroll
  for (int b = 0; b < 4; b++) {
    int js[4];
    #pragma unroll
    for (int q = 0; q < 4; q++) {
      const int ek = b * 4 + q;
      js[q] = (ek < DEG_) ? es[ek] : i;
    }
    float g[4][2];
    #pragma unroll
    for (int q = 0; q < 4; q++) {
      const float2 v = *(const float2*)(gl + (size_t)js[q] * 512 + cb);
      g[q][0] = v.x; g[q][1] = v.y;
    }
    float p[4];
    #pragma unroll
    for (int q = 0; q < 4; q++) {
      const float z0 = g[q][0] + gr0;
      const float z1 = g[q][1] + gr1;
      float s = z0 * a60;
      s = fmaf(fabsf(z0), a40, s);
      s = fmaf(z1, a61, s);
      s = fmaf(fabsf(z1), a41, s);
      p[q] = s;
    }
    #pragma unroll
    for (int q = 0; q < 4; q++) {     // full-wave reduce (64 lanes = 1 head)
      p[q] = row_reduce16(p[q]);
      p[q] += __shfl_xor(p[q], 16);
      p[q] += __shfl_xor(p[q], 32);
    }
    const float bmax = fmaxf(fmaxf(p[0], p[1]), fmaxf(p[2], p[3]));
    const float nm   = fmaxf(m, bmax);
    const float sc   = exp2f(m - nm);   // 0 on first batch
    den *= sc; acc0 *= sc; acc1 *= sc;
    #pragma unroll
    for (int q = 0; q < 4; q++) {
      const float w = exp2f(p[q] - nm);
      den += w;
      acc0 = fmaf(w, g[q][0], acc0);
      acc1 = fmaf(w, g[q][1], acc1);
    }
    m = nm;
  }

  const float inv = 0.25f / den;        // per-head normalizer * head-mean
  smem[h][lane * 2]     = acc0 * inv;
  smem[h][lane * 2 + 1] = acc1 * inv;
  __syncthreads();

  if (h == 0) {
    const int c = lane * 2;
    float s0 = smem[0][c] + smem[1][c] + smem[2][c] + smem[3][c];
    float s1 = smem[0][c + 1] + smem[1][c + 1] + smem[2][c + 1] + smem[3][c + 1];
    s0 = elu1(s0 + bias[c]);
    s1 = elu1(s1 + bias[c + 1]);
    *(float2*)(out + (size_t)gid * 128 + c) = make_float2(s0, s1);
  }
}

// ---------------------------------------------------------------------------
extern "C" void kernel_launch(void* const* d_in, const int* in_sizes, int n_in,
                              void* d_out, int out_size, void* d_ws, size_t ws_size,
                              hipStream_t stream)
{
  (void)in_sizes; (void)n_in; (void)out_size; (void)ws_size;

  const float* x  = (const float*)d_in[0];
  const int*   es = (const int*)d_in[1];
  const float *c1_wl=(const float*)d_in[3], *c1_wr=(const float*)d_in[4], *c1_a=(const float*)d_in[5], *c1_b=(const float*)d_in[6];
  const float *c2_wl=(const float*)d_in[7], *c2_wr=(const float*)d_in[8], *c2_a=(const float*)d_in[9], *c2_b=(const float*)d_in[10];
  const float *c3_wl=(const float*)d_in[11],*c3_wr=(const float*)d_in[12],*c3_a=(const float*)d_in[13],*c3_b=(const float*)d_in[14];
  const float *c4_wl=(const float*)d_in[15],*c4_wr=(const float*)d_in[16],*c4_a=(const float*)d_in[17],*c4_b=(const float*)d_in[18];
  const float *r11_wl=(const float*)d_in[19],*r11_wr=(const float*)d_in[20],*r11_a=(const float*)d_in[21],*r11_b=(const float*)d_in[22];
  const float *r12_wl=(const float*)d_in[23],*r12_wr=(const float*)d_in[24],*r12_a=(const float*)d_in[25],*r12_b=(const float*)d_in[26];
  const float *r2_wl=(const float*)d_in[27],*r2_wr=(const float*)d_in[28],*r2_a=(const float*)d_in[29],*r2_b=(const float*)d_in[30];
  const float *f11_wl=(const float*)d_in[31],*f11_wr=(const float*)d_in[32],*f11_a=(const float*)d_in[33],*f11_b=(const float*)d_in[34];
  const float *f2_wl=(const float*)d_in[35],*f2_wr=(const float*)d_in[36],*f2_a=(const float*)d_in[37],*f2_b=(const float*)d_in[38];
  const float *r3_w=(const float*)d_in[39], *r3_b=(const float*)d_in[40];
  const float *f3_w=(const float*)d_in[41], *f3_b=(const float*)d_in[42];
  const float *r4_w=(const float*)d_in[43], *r4_b=(const float*)d_in[44];
  const float *f4_w=(const float*)d_in[45], *f4_b=(const float*)d_in[46];

  float* ws = (float*)d_ws;
  float* GL = ws;
  float* GR = GL + (size_t)16777216;
  float* A0 = GR + (size_t)16777216;            // [T,N,128]
  float* A1 = A0 + (size_t)T_ * N_ * 128;       // [T,N,64]
  float* B0 = A1 + (size_t)T_ * N_ * 64;        // [N,128]
  float* B1 = B0 + (size_t)N_ * 128;            // [N,128]
  ushort* SH = (ushort*)(B1 + (size_t)N_ * 128);        // split A hi (max T*N*128)
  ushort* SL = SH + (size_t)8388608;                    // split A lo
  ushort* WH = SL + (size_t)8388608;                    // split W hi [2][HC][K]
  ushort* WL = WH + (size_t)131072;                     // split W lo

  float* recon = (float*)d_out;
  float* fcst  = recon + (size_t)N_ * 64;
  float* emb   = fcst + (size_t)N_ * 64;        // [T,N,64]

  const dim3 blk(256);

  // ---- c1: 64 -> 128 (HC=512), 2 GEMM chunks of 4 timesteps ----
  split_x<<<dim3((T_ * N_ * 64 / 4 + 255) / 256), blk, 0, stream>>>(x, SH, SL, T_ * N_ * 64 / 4);
  split_wt<<<dim3((2 * 512 * 64 + 255) / 256), blk, 0, stream>>>(c1_wl, c1_wr, WH, WL, 64, 512);
  for (int ch = 0; ch < 2; ch++) {
    const int t0 = ch * 4, nt = 4;
    gemm_mfma<<<dim3(N_ / 128, 8, 2 * nt), blk, 0, stream>>>(
        SH + (size_t)t0 * N_ * 64, SL + (size_t)t0 * N_ * 64, WH, WL, GL, GR, N_, 512, 64, nt);
    gat_agg512<<<dim3(nt * N_), blk, 0, stream>>>(
        GL, GR, c1_a, c1_b, es + (size_t)t0 * E_, A0 + (size_t)t0 * N_ * 128);
  }
  // ---- c2: 128 -> 64 (HC=256); A1 split fused into agg ----
  split_x<<<dim3((T_ * N_ * 128 / 4 + 255) / 256), blk, 0, stream>>>(A0, SH, SL, T_ * N_ * 128 / 4);
  split_wt<<<dim3((2 * 256 * 128 + 255) / 256), blk, 0, stream>>>(c2_wl, c2_wr, WH, WL, 128, 256);
  gemm_mfma<<<dim3(N_ / 128, 4, 2 * T_), blk, 0, stream>>>(SH, SL, WH, WL, GL, GR, N_, 256, 128, T_);
  gat_agg256<false><<<dim3(T_ * N_ / 4), blk, 0, stream>>>(GL, GR, c2_a, c2_b, es, A1, nullptr, SH, SL, T_ * N_);
  // ---- c3: 64 -> 64 (HC=256), concat with elu(emb2); A0 split fused ----
  split_wt<<<dim3((2 * 256 * 64 + 255) / 256), blk, 0, stream>>>(c3_wl, c3_wr, WH, WL, 64, 256);
  gemm_mfma<<<dim3(N_ / 128, 4, 2 * T_), blk, 0, stream>>>(SH, SL, WH, WL, GL, GR, N_, 256, 64, T_);
  gat_agg256<true><<<dim3(T_ * N_ / 4), blk, 0, stream>>>(GL, GR, c3_a, c3_b, es, A0, A1, SH, SL, T_ * N_);
  // ---- c4: 128 -> 64 (HC=256) -> emb; emb split fused (full [T,N,64]) ----
  split_wt<<<dim3((2 * 256 * 128 + 255) / 256), blk, 0, stream>>>(c4_wl, c4_wr, WH, WL, 128, 256);
  gemm_mfma<<<dim3(N_ / 128, 4, 2 * T_), blk, 0, stream>>>(SH, SL, WH, WL, GL, GR, N_, 256, 128, T_);
  gat_agg256<false><<<dim3(T_ * N_ / 4), blk, 0, stream>>>(GL, GR, c4_a, c4_b, es, emb, nullptr, SH, SL, T_ * N_);

  // ---- reconstruction branch (edges at t = 7; emb split slice 7 in SH/SL) ----
  const int* esR = es + (size_t)7 * E_;
  split_wt<<<dim3((2 * 256 * 64 + 255) / 256), blk, 0, stream>>>(r11_wl, r11_wr, WH, WL, 64, 256);
  gemm_mfma<<<dim3(N_ / 128, 4, 2), blk, 0, stream>>>(SH + (size_t)7 * N_ * 64, SL + (size_t)7 * N_ * 64, WH, WL, GL, GR, N_, 256, 64, 1);
  gat_agg256<false><<<dim3(N_ / 4), blk, 0, stream>>>(GL, GR, r11_a, r11_b, esR, B0, nullptr, SH, SL, N_);
  split_wt<<<dim3((2 * 256 * 64 + 255) / 256), blk, 0, stream>>>(r12_wl, r12_wr, WH, WL, 64, 256);
  gemm_mfma<<<dim3(N_ / 128, 4, 2), blk, 0, stream>>>(SH, SL, WH, WL, GL, GR, N_, 256, 64, 1);
  gat_agg256<true><<<dim3(N_ / 4), blk, 0, stream>>>(GL, GR, r12_a, r12_b, esR, B1, B0, SH, SL, N_);
  split_wt<<<dim3((2 * 512 * 128 + 255) / 256), blk, 0, stream>>>(r2_wl, r2_wr, WH, WL, 128, 512);
  gemm_mfma<<<dim3(N_ / 128, 8, 2), blk, 0, stream>>>(SH, SL, WH, WL, GL, GR, N_, 512, 128, 1);
  gat_agg512<<<dim3(N_), blk, 0, stream>>>(GL, GR, r2_a, r2_b, esR, B0);
  gemm_k<1><<<dim3(N_ / 64, 1, 1), blk, 0, stream>>>(B0, r3_w, B1, r3_b, N_, 64, 128);
  gemm_k<2><<<dim3(N_ / 64, 1, 1), blk, 0, stream>>>(B1, r4_w, recon, r4_b, N_, 64, 64);

  // ---- forecasting branch (edges at t = 6; emb split slice 6 intact) ----
  const int* esF = es + (size_t)6 * E_;
  split_wt<<<dim3((2 * 256 * 64 + 255) / 256), blk, 0, stream>>>(f11_wl, f11_wr, WH, WL, 64, 256);
  gemm_mfma<<<dim3(N_ / 128, 4, 2), blk, 0, stream>>>(SH + (size_t)6 * N_ * 64, SL + (size_t)6 * N_ * 64, WH, WL, GL, GR, N_, 256, 64, 1);
  gat_agg256<false><<<dim3(N_ / 4), blk, 0, stream>>>(GL, GR, f11_a, f11_b, esF, B0, nullptr, SH, SL, N_);
  split_wt<<<dim3((2 * 256 * 64 + 255) / 256), blk, 0, stream>>>(r12_wl, r12_wr, WH, WL, 64, 256);
  gemm_mfma<<<dim3(N_ / 128, 4, 2), blk, 0, stream>>>(SH, SL, WH, WL, GL, GR, N_, 256, 64, 1);
  gat_agg256<true><<<dim3(N_ / 4), blk, 0, stream>>>(GL, GR, r12_a, r12_b, esF, B1, B0, SH, SL, N_);
  split_wt<<<dim3((2 * 512 * 128 + 255) / 256), blk, 0, stream>>>(f2_wl, f2_wr, WH, WL, 128, 512);
  gemm_mfma<<<dim3(N_ / 128, 8, 2), blk, 0, stream>>>(SH, SL, WH, WL, GL, GR, N_, 512, 128, 1);
  gat_agg512<<<dim3(N_), blk, 0, stream>>>(GL, GR, f2_a, f2_b, esF, B0);
  gemm_k<1><<<dim3(N_ / 64, 1, 1), blk, 0, stream>>>(B0, f3_w, B1, f3_b, N_, 64, 128);
  gemm_k<2><<<dim3(N_ / 64, 1, 1), blk, 0, stream>>>(B1, f4_w, fcst, f4_b, N_, 64, 64);
}

// Round 9
// 1011.271 us; speedup vs baseline: 1.3922x; 1.0249x over previous
//
#include <hip/hip_runtime.h>
#include <cmath>

// Problem constants (from reference setup_inputs)
constexpr int T_   = 8;
constexpr int N_   = 8192;
constexpr int DEG_ = 15;
constexpr int E_   = N_ * (DEG_ + 1);   // 131072 edges per timestep
constexpr float L2E_ = 1.44269504f;

// fast ELU: expm1 via exp2 (abs err ~1e-7, threshold 7e-4)
__device__ __forceinline__ float elu1(float v) {
  return v > 0.f ? v : exp2f(v * L2E_) - 1.f;
}

typedef __attribute__((ext_vector_type(8))) short bf16x8;
typedef __attribute__((ext_vector_type(4))) float f32x4;

__device__ __forceinline__ ushort f2bf(float x) {
  uint u = __float_as_uint(x);
  return (ushort)((u + 0x7FFFu + ((u >> 16) & 1u)) >> 16);
}
__device__ __forceinline__ float bf2f(ushort h) {
  return __uint_as_float(((uint)h) << 16);
}

// v_add with DPP row_ror: sum over each 16-lane row after steps 1,2,4,8.
template<int CTRL>
__device__ __forceinline__ float dpp_add(float x) {
  const int t = __builtin_amdgcn_mov_dpp(__float_as_int(x), CTRL, 0xf, 0xf, true);
  return x + __int_as_float(t);
}
__device__ __forceinline__ float row_reduce16(float x) {
  x = dpp_add<0x121>(x);   // row_ror:1
  x = dpp_add<0x122>(x);   // row_ror:2
  x = dpp_add<0x124>(x);   // row_ror:4
  x = dpp_add<0x128>(x);   // row_ror:8
  return x;
}

// ---------------------------------------------------------------------------
// split_x: fp32 array -> hi/lo bf16 arrays (same layout). 4 elems/thread.
// ---------------------------------------------------------------------------
__global__ __launch_bounds__(256) void split_x(
    const float* __restrict__ X, ushort* __restrict__ XH, ushort* __restrict__ XL, int n4)
{
  const int i = blockIdx.x * 256 + threadIdx.x;
  if (i >= n4) return;
  const float4 v = ((const float4*)X)[i];
  const ushort h0 = f2bf(v.x), h1 = f2bf(v.y), h2 = f2bf(v.z), h3 = f2bf(v.w);
  ushort4 hh; hh.x = h0; hh.y = h1; hh.z = h2; hh.w = h3;
  ushort4 ll;
  ll.x = f2bf(v.x - bf2f(h0)); ll.y = f2bf(v.y - bf2f(h1));
  ll.z = f2bf(v.z - bf2f(h2)); ll.w = f2bf(v.w - bf2f(h3));
  ((ushort4*)XH)[i] = hh;
  ((ushort4*)XL)[i] = ll;
}

// ---------------------------------------------------------------------------
// split_wt: W_l, W_r [K, HC] fp32 -> WH/WL [2][HC][K] bf16 (transposed).
// ---------------------------------------------------------------------------
__global__ __launch_bounds__(256) void split_wt(
    const float* __restrict__ Wl, const float* __restrict__ Wr,
    ushort* __restrict__ WH, ushort* __restrict__ WL, int K, int HC)
{
  const int idx = blockIdx.x * 256 + threadIdx.x;
  if (idx >= 2 * HC * K) return;
  const int k = idx % K;
  const int n = (idx / K) % HC;
  const int s = idx / (K * HC);
  const float v = (s ? Wr : Wl)[k * HC + n];
  const ushort h = f2bf(v);
  WH[idx] = h;
  WL[idx] = f2bf(v - bf2f(h));
}

// ---------------------------------------------------------------------------
// MFMA GEMM (split-bf16): C = A @ W, A hi/lo [nt][M][K] bf16, W hi/lo
// [2][Ncol][K] bf16 (transposed). x.w ~= ah.wh + ah.wl + al.wh.
// BM=128, BN=64, BK=32; 256 thr = 4 waves.
// ---------------------------------------------------------------------------
__global__ __launch_bounds__(256) void gemm_mfma(
    const ushort* __restrict__ Ah, const ushort* __restrict__ Al,
    const ushort* __restrict__ Wh, const ushort* __restrict__ Wl,
    float* __restrict__ Cl, float* __restrict__ Cr,
    int M, int Ncol, int K, int nt)
{
  __shared__ alignas(16) ushort lAh[4 * 1032];
  __shared__ alignas(16) ushort lAl[4 * 1032];
  __shared__ alignas(16) ushort lBh[4 * 520];
  __shared__ alignas(16) ushort lBl[4 * 520];

  const int z = blockIdx.z;
  const int t = (z < nt) ? z : z - nt;
  const int side = (z < nt) ? 0 : 1;
  const ushort* __restrict__ Bh = Wh + (size_t)side * Ncol * K;
  const ushort* __restrict__ Bl = Wl + (size_t)side * Ncol * K;
  float* __restrict__ C = (side ? Cr : Cl) + (size_t)t * M * Ncol;
  const size_t aoff = (size_t)t * M * K;

  const int bm = blockIdx.x * 128, bn = blockIdx.y * 64;
  const int tid = threadIdx.x;
  const int wid = tid >> 6, lane = tid & 63;
  const int l15 = lane & 15, lk = lane >> 4;

  f32x4 acc[2][4] = {};

  for (int k0 = 0; k0 < K; k0 += 32) {
    #pragma unroll
    for (int c = 0; c < 2; c++) {
      const int ch = tid + c * 256;
      const int row = ch >> 2, kc = ch & 3;
      const size_t ga = aoff + (size_t)(bm + row) * K + (k0 + kc * 8);
      *(uint4*)&lAh[kc * 1032 + row * 8] = *(const uint4*)(Ah + ga);
      *(uint4*)&lAl[kc * 1032 + row * 8] = *(const uint4*)(Al + ga);
    }
    {
      const int col = tid >> 2, kc = tid & 3;
      const size_t gb = (size_t)(bn + col) * K + (k0 + kc * 8);
      *(uint4*)&lBh[kc * 520 + col * 8] = *(const uint4*)(Bh + gb);
      *(uint4*)&lBl[kc * 520 + col * 8] = *(const uint4*)(Bl + gb);
    }
    __syncthreads();

    bf16x8 ah[2], al[2], bh4[4], bl4[4];
    const int r0 = wid * 32;
    #pragma unroll
    for (int rf = 0; rf < 2; rf++) {
      const int ro = (r0 + rf * 16 + l15) * 8;
      ah[rf] = *(const bf16x8*)&lAh[lk * 1032 + ro];
      al[rf] = *(const bf16x8*)&lAl[lk * 1032 + ro];
    }
    #pragma unroll
    for (int cf = 0; cf < 4; cf++) {
      const int co = (cf * 16 + l15) * 8;
      bh4[cf] = *(const bf16x8*)&lBh[lk * 520 + co];
      bl4[cf] = *(const bf16x8*)&lBl[lk * 520 + co];
    }
    #pragma unroll
    for (int rf = 0; rf < 2; rf++)
      #pragma unroll
      for (int cf = 0; cf < 4; cf++) {
        acc[rf][cf] = __builtin_amdgcn_mfma_f32_16x16x32_bf16(ah[rf], bh4[cf], acc[rf][cf], 0, 0, 0);
        acc[rf][cf] = __builtin_amdgcn_mfma_f32_16x16x32_bf16(ah[rf], bl4[cf], acc[rf][cf], 0, 0, 0);
        acc[rf][cf] = __builtin_amdgcn_mfma_f32_16x16x32_bf16(al[rf], bh4[cf], acc[rf][cf], 0, 0, 0);
      }
    __syncthreads();
  }

  #pragma unroll
  for (int rf = 0; rf < 2; rf++)
    #pragma unroll
    for (int cf = 0; cf < 4; cf++) {
      const int col = bn + cf * 16 + l15;
      #pragma unroll
      for (int reg = 0; reg < 4; reg++) {
        const int row = bm + wid * 32 + rf * 16 + lk * 4 + reg;
        C[(size_t)row * Ncol + col] = acc[rf][cf][reg];
      }
    }
}

// ---------------------------------------------------------------------------
// Small fp32 GEMM for the N=64 epilogue layers (64x64 tile, 4x4/thread).
// ---------------------------------------------------------------------------
template<int EPI>   // 1 = +bias tanh, 2 = +bias
__global__ __launch_bounds__(256) void gemm_k(
    const float* __restrict__ A, const float* __restrict__ B,
    float* __restrict__ C, const float* __restrict__ bias,
    int M, int Ncol, int K)
{
  __shared__ float As[16][68];
  __shared__ float Bs[16][64];

  const int tid = threadIdx.x;
  const int tx = tid & 15, ty = tid >> 4;
  const int bm = blockIdx.x * 64, bn = blockIdx.y * 64;

  const int arow = tid >> 2;
  const int akc  = (tid & 3) * 4;
  const int brow = tid >> 4;
  const int bc4  = (tid & 15) * 4;

  float acc[4][4];
  #pragma unroll
  for (int i = 0; i < 4; i++)
    #pragma unroll
    for (int j = 0; j < 4; j++) acc[i][j] = 0.f;

  for (int k0 = 0; k0 < K; k0 += 16) {
    const float4 va = *(const float4*)(A + (size_t)(bm + arow) * K + (k0 + akc));
    const float4 vb = *(const float4*)(B + (size_t)(k0 + brow) * Ncol + (bn + bc4));
    As[akc + 0][arow] = va.x; As[akc + 1][arow] = va.y;
    As[akc + 2][arow] = va.z; As[akc + 3][arow] = va.w;
    *(float4*)&Bs[brow][bc4] = vb;
    __syncthreads();
    #pragma unroll
    for (int kk = 0; kk < 16; kk++) {
      const float4 av = *(const float4*)&As[kk][ty * 4];
      const float4 bv = *(const float4*)&Bs[kk][tx * 4];
      const float a4[4] = {av.x, av.y, av.z, av.w};
      const float b4[4] = {bv.x, bv.y, bv.z, bv.w};
      #pragma unroll
      for (int i = 0; i < 4; i++)
        #pragma unroll
        for (int j = 0; j < 4; j++)
          acc[i][j] = fmaf(a4[i], b4[j], acc[i][j]);
    }
    __syncthreads();
  }

  #pragma unroll
  for (int i = 0; i < 4; i++) {
    const int row = bm + ty * 4 + i;
    const int col = bn + tx * 4;
    float v[4] = {acc[i][0], acc[i][1], acc[i][2], acc[i][3]};
    #pragma unroll
    for (int j = 0; j < 4; j++) v[j] += bias[col + j];
    if (EPI == 1) {
      #pragma unroll
      for (int j = 0; j < 4; j++) v[j] = tanhf(v[j]);
    }
    *(float4*)(C + (size_t)row * Ncol + col) = make_float4(v[0], v[1], v[2], v[3]);
  }
}

// ---------------------------------------------------------------------------
// GATv2 aggregation, HC=256 (cout=64): 1 wave per node, 4 nodes/block.
// Lane l owns channels [4l,4l+4); 16-lane group = head. Edges in 4 batches
// of 4; online max-subtracted softmax at batch granularity; scores in log2
// domain (0.6*L2E / 0.4*L2E baked into attention weights).
// t is block-uniform (blockIdx>>11) so gl is an SGPR base; gather offsets
// are 32-bit (js<<10 | lane<<4) -> global_load saddr+voffset (1 VALU/gather).
// WF32: write fp32 out row. Always writes bf16 hi/lo split (SHo/SLo).
// ---------------------------------------------------------------------------
template<bool CONCAT, bool WF32>
__global__ __launch_bounds__(256) void gat_agg256(
    const float* __restrict__ GL, const float* __restrict__ GR,
    const float* __restrict__ aw_, const float* __restrict__ bias,
    const int* __restrict__ esrc, float* __restrict__ out,
    const float* __restrict__ csrc,
    ushort* __restrict__ SHo, ushort* __restrict__ SLo, int numNodes)
{
  constexpr int HC = 256, C = 64;
  constexpr int OSTR = CONCAT ? 128 : 64;

  const int lane = threadIdx.x & 63;
  const int wid  = threadIdx.x >> 6;
  const int t    = blockIdx.x >> 11;          // block-uniform (8192/4 blocks per t)
  const int gid  = blockIdx.x * 4 + wid;
  if (gid >= numNodes) return;
  const int i = gid & (N_ - 1);

  const float* __restrict__ gl = GL + (size_t)t * N_ * HC;
  const int*   __restrict__ es = esrc + (size_t)t * E_ + (size_t)i * DEG_;
  const uint lo16 = (uint)lane << 4;          // lane*16 bytes

  float gr[4], a6[4], a4c[4];
  {
    const float4 gv = *(const float4*)(GR + (size_t)gid * HC + lane * 4);
    const float4 av = *(const float4*)(aw_ + lane * 4);
    gr[0] = gv.x; gr[1] = gv.y; gr[2] = gv.z; gr[3] = gv.w;
    a6[0] = 0.6f * L2E_ * av.x; a6[1] = 0.6f * L2E_ * av.y;
    a6[2] = 0.6f * L2E_ * av.z; a6[3] = 0.6f * L2E_ * av.w;
    a4c[0] = 0.4f * L2E_ * av.x; a4c[1] = 0.4f * L2E_ * av.y;
    a4c[2] = 0.4f * L2E_ * av.z; a4c[3] = 0.4f * L2E_ * av.w;
  }

  float acc[4] = {0.f, 0.f, 0.f, 0.f};
  float den = 0.f, m = -1e30f;

  #pragma unroll
  for (int b = 0; b < 4; b++) {
    uint off[4];
    #pragma unroll
    for (int q = 0; q < 4; q++) {
      const int ek = b * 4 + q;
      const uint j = (uint)((ek < DEG_) ? es[ek] : i);
      off[q] = (j << 10) + lo16;              // row stride 1024 B
    }
    float g[4][4];
    #pragma unroll
    for (int q = 0; q < 4; q++) {
      const float4 v = *(const float4*)((const char*)gl + off[q]);
      g[q][0] = v.x; g[q][1] = v.y; g[q][2] = v.z; g[q][3] = v.w;
    }
    float p[4];
    #pragma unroll
    for (int q = 0; q < 4; q++) {
      float s = 0.f;
      #pragma unroll
      for (int u = 0; u < 4; u++) {
        const float z = g[q][u] + gr[u];
        s = fmaf(z, a6[u], s);
        s = fmaf(fabsf(z), a4c[u], s);
      }
      p[q] = s;
    }
    #pragma unroll
    for (int q = 0; q < 4; q++) p[q] = row_reduce16(p[q]);

    const float bmax = fmaxf(fmaxf(p[0], p[1]), fmaxf(p[2], p[3]));
    const float nm   = fmaxf(m, bmax);
    const float sc   = exp2f(m - nm);     // 0 on first batch
    den *= sc;
    #pragma unroll
    for (int u = 0; u < 4; u++) acc[u] *= sc;
    #pragma unroll
    for (int q = 0; q < 4; q++) {
      const float w = exp2f(p[q] - nm);
      den += w;
      #pragma unroll
      for (int u = 0; u < 4; u++) acc[u] = fmaf(w, g[q][u], acc[u]);
    }
    m = nm;
  }

  const float inv = 0.25f / den;          // per-head normalizer * head-mean
  #pragma unroll
  for (int u = 0; u < 4; u++) acc[u] *= inv;
  #pragma unroll
  for (int u = 0; u < 4; u++) {
    acc[u] += __shfl_xor(acc[u], 16);
    acc[u] += __shfl_xor(acc[u], 32);
  }

  if (lane < 16) {
    float o[4];
    #pragma unroll
    for (int u = 0; u < 4; u++)
      o[u] = elu1(acc[u] + bias[lane * 4 + u]);
    if (WF32)
      *(float4*)(out + (size_t)gid * OSTR + lane * 4) = make_float4(o[0], o[1], o[2], o[3]);
    ushort4 hh, ll;
    hh.x = f2bf(o[0]); hh.y = f2bf(o[1]); hh.z = f2bf(o[2]); hh.w = f2bf(o[3]);
    ll.x = f2bf(o[0] - bf2f(hh.x)); ll.y = f2bf(o[1] - bf2f(hh.y));
    ll.z = f2bf(o[2] - bf2f(hh.z)); ll.w = f2bf(o[3] - bf2f(hh.w));
    *(ushort4*)(SHo + (size_t)gid * OSTR + lane * 4) = hh;
    *(ushort4*)(SLo + (size_t)gid * OSTR + lane * 4) = ll;
  } else if (CONCAT && lane < 32) {
    const int q = lane - 16;
    const float4 v = *(const float4*)(csrc + (size_t)gid * C + q * 4);
    const float o0 = elu1(v.x), o1 = elu1(v.y), o2 = elu1(v.z), o3 = elu1(v.w);
    if (WF32)
      *(float4*)(out + (size_t)gid * OSTR + C + q * 4) = make_float4(o0, o1, o2, o3);
    ushort4 hh, ll;
    hh.x = f2bf(o0); hh.y = f2bf(o1); hh.z = f2bf(o2); hh.w = f2bf(o3);
    ll.x = f2bf(o0 - bf2f(hh.x)); ll.y = f2bf(o1 - bf2f(hh.y));
    ll.z = f2bf(o2 - bf2f(hh.z)); ll.w = f2bf(o3 - bf2f(hh.w));
    *(ushort4*)(SHo + (size_t)gid * OSTR + C + q * 4) = hh;
    *(ushort4*)(SLo + (size_t)gid * OSTR + C + q * 4) = ll;
  }
}

// ---------------------------------------------------------------------------
// GATv2 aggregation, HC=512 (cout=128): 1 node per block, 1 head per wave.
// Lane l owns channels [2l,2l+2). r5 structure (batched loads, online batch
// softmax). 32-bit gather offsets (js<<11 | lane<<3), SGPR gl base.
// WF32: write fp32 out. SPLIT: write bf16 hi/lo split (out stride 128).
// ---------------------------------------------------------------------------
template<bool WF32, bool SPLIT>
__global__ __launch_bounds__(256) void gat_agg512(
    const float* __restrict__ GL, const float* __restrict__ GR,
    const float* __restrict__ aw_, const float* __restrict__ bias,
    const int* __restrict__ esrc, float* __restrict__ out,
    ushort* __restrict__ SHo, ushort* __restrict__ SLo)
{
  __shared__ float smem[4][128];

  const int lane = threadIdx.x & 63;
  const int h    = threadIdx.x >> 6;
  const int gid  = blockIdx.x;
  const int t = gid >> 13;
  const int i = gid & (N_ - 1);

  const float* __restrict__ gl = GL + (size_t)t * N_ * 512;
  const int*   __restrict__ es = esrc + (size_t)t * E_ + (size_t)i * DEG_;
  const int cb = h * 128 + lane * 2;
  const uint cbo = (uint)cb << 2;             // byte offset within row

  float gr0, gr1, a60, a61, a40, a41;
  {
    const float2 gv = *(const float2*)(GR + (size_t)gid * 512 + cb);
    const float2 av = *(const float2*)(aw_ + cb);
    gr0 = gv.x; gr1 = gv.y;
    a60 = 0.6f * L2E_ * av.x; a61 = 0.6f * L2E_ * av.y;
    a40 = 0.4f * L2E_ * av.x; a41 = 0.4f * L2E_ * av.y;
  }

  float acc0 = 0.f, acc1 = 0.f, den = 0.f, m = -1e30f;

  #pragma unroll
  for (int b = 0; b < 4; b++) {
    uint off[4];
    #pragma unroll
    for (int q = 0; q < 4; q++) {
      const int ek = b * 4 + q;
      const uint j = (uint)((ek < DEG_) ? es[ek] : i);
      off[q] = (j << 11) + cbo;               // row stride 2048 B
    }
    float g[4][2];
    #pragma unroll
    for (int q = 0; q < 4; q++) {
      const float2 v = *(const float2*)((const char*)gl + off[q]);
      g[q][0] = v.x; g[q][1] = v.y;
    }
    float p[4];
    #pragma unroll
    for (int q = 0; q < 4; q++) {
      const float z0 = g[q][0] + gr0;
      const float z1 = g[q][1] + gr1;
      float s = z0 * a60;
      s = fmaf(fabsf(z0), a40, s);
      s = fmaf(z1, a61, s);
      s = fmaf(fabsf(z1), a41, s);
      p[q] = s;
    }
    #pragma unroll
    for (int q = 0; q < 4; q++) {     // full-wave reduce (64 lanes = 1 head)
      p[q] = row_reduce16(p[q]);
      p[q] += __shfl_xor(p[q], 16);
      p[q] += __shfl_xor(p[q], 32);
    }
    const float bmax = fmaxf(fmaxf(p[0], p[1]), fmaxf(p[2], p[3]));
    const float nm   = fmaxf(m, bmax);
    const float sc   = exp2f(m - nm);   // 0 on first batch
    den *= sc; acc0 *= sc; acc1 *= sc;
    #pragma unroll
    for (int q = 0; q < 4; q++) {
      const float w = exp2f(p[q] - nm);
      den += w;
      acc0 = fmaf(w, g[q][0], acc0);
      acc1 = fmaf(w, g[q][1], acc1);
    }
    m = nm;
  }

  const float inv = 0.25f / den;        // per-head normalizer * head-mean
  smem[h][lane * 2]     = acc0 * inv;
  smem[h][lane * 2 + 1] = acc1 * inv;
  __syncthreads();

  if (h == 0) {
    const int c = lane * 2;
    float s0 = smem[0][c] + smem[1][c] + smem[2][c] + smem[3][c];
    float s1 = smem[0][c + 1] + smem[1][c + 1] + smem[2][c + 1] + smem[3][c + 1];
    s0 = elu1(s0 + bias[c]);
    s1 = elu1(s1 + bias[c + 1]);
    if (WF32)
      *(float2*)(out + (size_t)gid * 128 + c) = make_float2(s0, s1);
    if (SPLIT) {
      ushort2 hh, ll;
      hh.x = f2bf(s0); hh.y = f2bf(s1);
      ll.x = f2bf(s0 - bf2f(hh.x)); ll.y = f2bf(s1 - bf2f(hh.y));
      *(ushort2*)(SHo + (size_t)gid * 128 + c) = hh;
      *(ushort2*)(SLo + (size_t)gid * 128 + c) = ll;
    }
  }
}

// ---------------------------------------------------------------------------
extern "C" void kernel_launch(void* const* d_in, const int* in_sizes, int n_in,
                              void* d_out, int out_size, void* d_ws, size_t ws_size,
                              hipStream_t stream)
{
  (void)in_sizes; (void)n_in; (void)out_size; (void)ws_size;

  const float* x  = (const float*)d_in[0];
  const int*   es = (const int*)d_in[1];
  const float *c1_wl=(const float*)d_in[3], *c1_wr=(const float*)d_in[4], *c1_a=(const float*)d_in[5], *c1_b=(const float*)d_in[6];
  const float *c2_wl=(const float*)d_in[7], *c2_wr=(const float*)d_in[8], *c2_a=(const float*)d_in[9], *c2_b=(const float*)d_in[10];
  const float *c3_wl=(const float*)d_in[11],*c3_wr=(const float*)d_in[12],*c3_a=(const float*)d_in[13],*c3_b=(const float*)d_in[14];
  const float *c4_wl=(const float*)d_in[15],*c4_wr=(const float*)d_in[16],*c4_a=(const float*)d_in[17],*c4_b=(const float*)d_in[18];
  const float *r11_wl=(const float*)d_in[19],*r11_wr=(const float*)d_in[20],*r11_a=(const float*)d_in[21],*r11_b=(const float*)d_in[22];
  const float *r12_wl=(const float*)d_in[23],*r12_wr=(const float*)d_in[24],*r12_a=(const float*)d_in[25],*r12_b=(const float*)d_in[26];
  const float *r2_wl=(const float*)d_in[27],*r2_wr=(const float*)d_in[28],*r2_a=(const float*)d_in[29],*r2_b=(const float*)d_in[30];
  const float *f11_wl=(const float*)d_in[31],*f11_wr=(const float*)d_in[32],*f11_a=(const float*)d_in[33],*f11_b=(const float*)d_in[34];
  const float *f2_wl=(const float*)d_in[35],*f2_wr=(const float*)d_in[36],*f2_a=(const float*)d_in[37],*f2_b=(const float*)d_in[38];
  const float *r3_w=(const float*)d_in[39], *r3_b=(const float*)d_in[40];
  const float *f3_w=(const float*)d_in[41], *f3_b=(const float*)d_in[42];
  const float *r4_w=(const float*)d_in[43], *r4_b=(const float*)d_in[44];
  const float *f4_w=(const float*)d_in[45], *f4_b=(const float*)d_in[46];

  // Workspace layout
  float* ws = (float*)d_ws;
  float* GL = ws;                                       // 16.7M f
  float* GR = GL + (size_t)16777216;                    // 16.7M f
  float* A1 = GR + (size_t)16777216;                    // [T,N,64] emb2 fp32
  float* B0 = A1 + (size_t)T_ * N_ * 64;                // [N,128]
  float* B1 = B0 + (size_t)N_ * 128;                    // [N,128]
  ushort* SH  = (ushort*)(B1 + (size_t)N_ * 128);       // 8.4M u (split ping)
  ushort* SL  = SH + (size_t)8388608;
  ushort* SH2 = SL + (size_t)8388608;                   // 8.4M u (split pong)
  ushort* SL2 = SH2 + (size_t)8388608;
  ushort* WH  = SL2 + (size_t)8388608;                  // 131072 u
  ushort* WL  = WH + (size_t)131072;

  float* recon = (float*)d_out;
  float* fcst  = recon + (size_t)N_ * 64;
  float* emb   = fcst + (size_t)N_ * 64;        // [T,N,64]

  const dim3 blk(256);

  // ---- c1: 64 -> 128 (HC=512); out consumed only via split -> SH2/SL2 ----
  split_x<<<dim3(T_ * N_ * 64 / 4 / 256), blk, 0, stream>>>(x, SH, SL, T_ * N_ * 64 / 4);
  split_wt<<<dim3((2 * 512 * 64 + 255) / 256), blk, 0, stream>>>(c1_wl, c1_wr, WH, WL, 64, 512);
  for (int ch = 0; ch < 2; ch++) {
    const int t0 = ch * 4, nt = 4;
    gemm_mfma<<<dim3(N_ / 128, 8, 2 * nt), blk, 0, stream>>>(
        SH + (size_t)t0 * N_ * 64, SL + (size_t)t0 * N_ * 64, WH, WL, GL, GR, N_, 512, 64, nt);
    gat_agg512<false, true><<<dim3(nt * N_), blk, 0, stream>>>(
        GL, GR, c1_a, c1_b, es + (size_t)t0 * E_, nullptr,
        SH2 + (size_t)t0 * N_ * 128, SL2 + (size_t)t0 * N_ * 128);
  }
  // ---- c2: 128 -> 64; emb2 fp32 (concat src) + split -> SH/SL ----
  split_wt<<<dim3((2 * 256 * 128 + 255) / 256), blk, 0, stream>>>(c2_wl, c2_wr, WH, WL, 128, 256);
  gemm_mfma<<<dim3(N_ / 128, 4, 2 * T_), blk, 0, stream>>>(SH2, SL2, WH, WL, GL, GR, N_, 256, 128, T_);
  gat_agg256<false, true><<<dim3(T_ * N_ / 4), blk, 0, stream>>>(
      GL, GR, c2_a, c2_b, es, A1, nullptr, SH, SL, T_ * N_);
  // ---- c3: 64 -> 64, concat elu(emb2); out consumed only via split -> SH/SL ----
  split_wt<<<dim3((2 * 256 * 64 + 255) / 256), blk, 0, stream>>>(c3_wl, c3_wr, WH, WL, 64, 256);
  gemm_mfma<<<dim3(N_ / 128, 4, 2 * T_), blk, 0, stream>>>(SH, SL, WH, WL, GL, GR, N_, 256, 64, T_);
  gat_agg256<true, false><<<dim3(T_ * N_ / 4), blk, 0, stream>>>(
      GL, GR, c3_a, c3_b, es, nullptr, A1, SH, SL, T_ * N_);
  // ---- c4: 128 -> 64 -> emb (d_out) + split -> SH2/SL2 ----
  split_wt<<<dim3((2 * 256 * 128 + 255) / 256), blk, 0, stream>>>(c4_wl, c4_wr, WH, WL, 128, 256);
  gemm_mfma<<<dim3(N_ / 128, 4, 2 * T_), blk, 0, stream>>>(SH, SL, WH, WL, GL, GR, N_, 256, 128, T_);
  gat_agg256<false, true><<<dim3(T_ * N_ / 4), blk, 0, stream>>>(
      GL, GR, c4_a, c4_b, es, emb, nullptr, SH2, SL2, T_ * N_);

  // ---- reconstruction branch (edges at t = 7; emb split slice 7 in SH2/SL2) ----
  const int* esR = es + (size_t)7 * E_;
  split_wt<<<dim3((2 * 256 * 64 + 255) / 256), blk, 0, stream>>>(r11_wl, r11_wr, WH, WL, 64, 256);
  gemm_mfma<<<dim3(N_ / 128, 4, 2), blk, 0, stream>>>(
      SH2 + (size_t)7 * N_ * 64, SL2 + (size_t)7 * N_ * 64, WH, WL, GL, GR, N_, 256, 64, 1);
  gat_agg256<false, true><<<dim3(N_ / 4), blk, 0, stream>>>(
      GL, GR, r11_a, r11_b, esR, B0, nullptr, SH, SL, N_);
  split_wt<<<dim3((2 * 256 * 64 + 255) / 256), blk, 0, stream>>>(r12_wl, r12_wr, WH, WL, 64, 256);
  gemm_mfma<<<dim3(N_ / 128, 4, 2), blk, 0, stream>>>(SH, SL, WH, WL, GL, GR, N_, 256, 64, 1);
  gat_agg256<true, false><<<dim3(N_ / 4), blk, 0, stream>>>(
      GL, GR, r12_a, r12_b, esR, nullptr, B0, SH, SL, N_);
  split_wt<<<dim3((2 * 512 * 128 + 255) / 256), blk, 0, stream>>>(r2_wl, r2_wr, WH, WL, 128, 512);
  gemm_mfma<<<dim3(N_ / 128, 8, 2), blk, 0, stream>>>(SH, SL, WH, WL, GL, GR, N_, 512, 128, 1);
  gat_agg512<true, false><<<dim3(N_), blk, 0, stream>>>(GL, GR, r2_a, r2_b, esR, B0, nullptr, nullptr);
  gemm_k<1><<<dim3(N_ / 64, 1, 1), blk, 0, stream>>>(B0, r3_w, B1, r3_b, N_, 64, 128);
  gemm_k<2><<<dim3(N_ / 64, 1, 1), blk, 0, stream>>>(B1, r4_w, recon, r4_b, N_, 64, 64);

  // ---- forecasting branch (edges at t = 6; emb split slice 6 in SH2/SL2) ----
  const int* esF = es + (size_t)6 * E_;
  split_wt<<<dim3((2 * 256 * 64 + 255) / 256), blk, 0, stream>>>(f11_wl, f11_wr, WH, WL, 64, 256);
  gemm_mfma<<<dim3(N_ / 128, 4, 2), blk, 0, stream>>>(
      SH2 + (size_t)6 * N_ * 64, SL2 + (size_t)6 * N_ * 64, WH, WL, GL, GR, N_, 256, 64, 1);
  gat_agg256<false, true><<<dim3(N_ / 4), blk, 0, stream>>>(
      GL, GR, f11_a, f11_b, esF, B0, nullptr, SH, SL, N_);
  split_wt<<<dim3((2 * 256 * 64 + 255) / 256), blk, 0, stream>>>(r12_wl, r12_wr, WH, WL, 64, 256);
  gemm_mfma<<<dim3(N_ / 128, 4, 2), blk, 0, stream>>>(SH, SL, WH, WL, GL, GR, N_, 256, 64, 1);
  gat_agg256<true, false><<<dim3(N_ / 4), blk, 0, stream>>>(
      GL, GR, r12_a, r12_b, esF, nullptr, B0, SH, SL, N_);
  split_wt<<<dim3((2 * 512 * 128 + 255) / 256), blk, 0, stream>>>(f2_wl, f2_wr, WH, WL, 128, 512);
  gemm_mfma<<<dim3(N_ / 128, 8, 2), blk, 0, stream>>>(SH, SL, WH, WL, GL, GR, N_, 512, 128, 1);
  gat_agg512<true, false><<<dim3(N_), blk, 0, stream>>>(GL, GR, f2_a, f2_b, esF, B0, nullptr, nullptr);
  gemm_k<1><<<dim3(N_ / 64, 1, 1), blk, 0, stream>>>(B0, f3_w, B1, f3_b, N_, 64, 128);
  gemm_k<2><<<dim3(N_ / 64, 1, 1), blk, 0, stream>>>(B1, f4_w, fcst, f4_b, N_, 64, 64);
}

// Round 10
// 1001.498 us; speedup vs baseline: 1.4058x; 1.0098x over previous
//
#include <hip/hip_runtime.h>
#include <cmath>

// Problem constants (from reference setup_inputs)
constexpr int T_   = 8;
constexpr int N_   = 8192;
constexpr int DEG_ = 15;
constexpr int E_   = N_ * (DEG_ + 1);   // 131072 edges per timestep
constexpr float L2E_ = 1.44269504f;

// fast ELU: expm1 via exp2 (abs err ~1e-7, threshold 7e-4)
__device__ __forceinline__ float elu1(float v) {
  return v > 0.f ? v : exp2f(v * L2E_) - 1.f;
}

typedef __attribute__((ext_vector_type(8))) short bf16x8;
typedef __attribute__((ext_vector_type(4))) float f32x4;

__device__ __forceinline__ ushort f2bf(float x) {
  uint u = __float_as_uint(x);
  return (ushort)((u + 0x7FFFu + ((u >> 16) & 1u)) >> 16);
}
__device__ __forceinline__ float bf2f(ushort h) {
  return __uint_as_float(((uint)h) << 16);
}

// v_add with DPP row_ror: sum over each 16-lane row after steps 1,2,4,8.
template<int CTRL>
__device__ __forceinline__ float dpp_add(float x) {
  const int t = __builtin_amdgcn_mov_dpp(__float_as_int(x), CTRL, 0xf, 0xf, true);
  return x + __int_as_float(t);
}
__device__ __forceinline__ float row_reduce16(float x) {
  x = dpp_add<0x121>(x);   // row_ror:1
  x = dpp_add<0x122>(x);   // row_ror:2
  x = dpp_add<0x124>(x);   // row_ror:4
  x = dpp_add<0x128>(x);   // row_ror:8
  return x;
}

// ---------------------------------------------------------------------------
// pad_edges: es[T][N*DEG] -> es16[T][N][16] (15 edges + self loop), uint.
// ---------------------------------------------------------------------------
__global__ __launch_bounds__(256) void pad_edges(
    const int* __restrict__ es, uint* __restrict__ es16, int total)
{
  const int idx = blockIdx.x * 256 + threadIdx.x;
  if (idx >= total) return;
  const int t = idx >> 13, i = idx & (N_ - 1);
  const int* e = es + (size_t)t * E_ + (size_t)i * DEG_;
  uint o[16];
  #pragma unroll
  for (int k = 0; k < DEG_; k++) o[k] = (uint)e[k];
  o[15] = (uint)i;
  uint4* dst = (uint4*)(es16 + (size_t)idx * 16);
  dst[0] = make_uint4(o[0], o[1], o[2], o[3]);
  dst[1] = make_uint4(o[4], o[5], o[6], o[7]);
  dst[2] = make_uint4(o[8], o[9], o[10], o[11]);
  dst[3] = make_uint4(o[12], o[13], o[14], o[15]);
}

// ---------------------------------------------------------------------------
// split_x: fp32 array -> hi/lo bf16 arrays (same layout). 4 elems/thread.
// ---------------------------------------------------------------------------
__global__ __launch_bounds__(256) void split_x(
    const float* __restrict__ X, ushort* __restrict__ XH, ushort* __restrict__ XL, int n4)
{
  const int i = blockIdx.x * 256 + threadIdx.x;
  if (i >= n4) return;
  const float4 v = ((const float4*)X)[i];
  const ushort h0 = f2bf(v.x), h1 = f2bf(v.y), h2 = f2bf(v.z), h3 = f2bf(v.w);
  ushort4 hh; hh.x = h0; hh.y = h1; hh.z = h2; hh.w = h3;
  ushort4 ll;
  ll.x = f2bf(v.x - bf2f(h0)); ll.y = f2bf(v.y - bf2f(h1));
  ll.z = f2bf(v.z - bf2f(h2)); ll.w = f2bf(v.w - bf2f(h3));
  ((ushort4*)XH)[i] = hh;
  ((ushort4*)XL)[i] = ll;
}

// ---------------------------------------------------------------------------
// split_wt_all: all 9 weight pairs in one launch. grid.y = pair index.
// W [K,HC] fp32 -> [2][HC][K] bf16 hi/lo at off. K, HC are powers of 2.
// ---------------------------------------------------------------------------
struct WTable {
  const float* wl[9]; const float* wr[9];
  int lgK[9]; int lgHC[9]; int off[9];
};
__global__ __launch_bounds__(256) void split_wt_all(
    WTable tb, ushort* __restrict__ WH, ushort* __restrict__ WL)
{
  const int y = blockIdx.y;
  const int lgK = tb.lgK[y], lgHC = tb.lgHC[y];
  const int n2 = 2 << (lgK + lgHC);
  const int idx = blockIdx.x * 256 + threadIdx.x;
  if (idx >= n2) return;
  const int k = idx & ((1 << lgK) - 1);
  const int n = (idx >> lgK) & ((1 << lgHC) - 1);
  const int s = idx >> (lgK + lgHC);
  const float* W = s ? tb.wr[y] : tb.wl[y];
  const float v = W[((size_t)k << lgHC) + n];
  const ushort h = f2bf(v);
  WH[tb.off[y] + idx] = h;
  WL[tb.off[y] + idx] = f2bf(v - bf2f(h));
}

// ---------------------------------------------------------------------------
// MFMA GEMM (split-bf16): C = A @ W, A hi/lo [nt][M][K] bf16, W hi/lo
// [2][Ncol][K] bf16 (transposed). x.w ~= ah.wh + ah.wl + al.wh.
// BM=128, BN=64, BK=32; 256 thr = 4 waves.
// ---------------------------------------------------------------------------
__global__ __launch_bounds__(256) void gemm_mfma(
    const ushort* __restrict__ Ah, const ushort* __restrict__ Al,
    const ushort* __restrict__ Wh, const ushort* __restrict__ Wl,
    float* __restrict__ Cl, float* __restrict__ Cr,
    int M, int Ncol, int K, int nt)
{
  __shared__ alignas(16) ushort lAh[4 * 1032];
  __shared__ alignas(16) ushort lAl[4 * 1032];
  __shared__ alignas(16) ushort lBh[4 * 520];
  __shared__ alignas(16) ushort lBl[4 * 520];

  const int z = blockIdx.z;
  const int t = (z < nt) ? z : z - nt;
  const int side = (z < nt) ? 0 : 1;
  const ushort* __restrict__ Bh = Wh + (size_t)side * Ncol * K;
  const ushort* __restrict__ Bl = Wl + (size_t)side * Ncol * K;
  float* __restrict__ C = (side ? Cr : Cl) + (size_t)t * M * Ncol;
  const size_t aoff = (size_t)t * M * K;

  const int bm = blockIdx.x * 128, bn = blockIdx.y * 64;
  const int tid = threadIdx.x;
  const int wid = tid >> 6, lane = tid & 63;
  const int l15 = lane & 15, lk = lane >> 4;

  f32x4 acc[2][4] = {};

  for (int k0 = 0; k0 < K; k0 += 32) {
    #pragma unroll
    for (int c = 0; c < 2; c++) {
      const int ch = tid + c * 256;
      const int row = ch >> 2, kc = ch & 3;
      const size_t ga = aoff + (size_t)(bm + row) * K + (k0 + kc * 8);
      *(uint4*)&lAh[kc * 1032 + row * 8] = *(const uint4*)(Ah + ga);
      *(uint4*)&lAl[kc * 1032 + row * 8] = *(const uint4*)(Al + ga);
    }
    {
      const int col = tid >> 2, kc = tid & 3;
      const size_t gb = (size_t)(bn + col) * K + (k0 + kc * 8);
      *(uint4*)&lBh[kc * 520 + col * 8] = *(const uint4*)(Bh + gb);
      *(uint4*)&lBl[kc * 520 + col * 8] = *(const uint4*)(Bl + gb);
    }
    __syncthreads();

    bf16x8 ah[2], al[2], bh4[4], bl4[4];
    const int r0 = wid * 32;
    #pragma unroll
    for (int rf = 0; rf < 2; rf++) {
      const int ro = (r0 + rf * 16 + l15) * 8;
      ah[rf] = *(const bf16x8*)&lAh[lk * 1032 + ro];
      al[rf] = *(const bf16x8*)&lAl[lk * 1032 + ro];
    }
    #pragma unroll
    for (int cf = 0; cf < 4; cf++) {
      const int co = (cf * 16 + l15) * 8;
      bh4[cf] = *(const bf16x8*)&lBh[lk * 520 + co];
      bl4[cf] = *(const bf16x8*)&lBl[lk * 520 + co];
    }
    #pragma unroll
    for (int rf = 0; rf < 2; rf++)
      #pragma unroll
      for (int cf = 0; cf < 4; cf++) {
        acc[rf][cf] = __builtin_amdgcn_mfma_f32_16x16x32_bf16(ah[rf], bh4[cf], acc[rf][cf], 0, 0, 0);
        acc[rf][cf] = __builtin_amdgcn_mfma_f32_16x16x32_bf16(ah[rf], bl4[cf], acc[rf][cf], 0, 0, 0);
        acc[rf][cf] = __builtin_amdgcn_mfma_f32_16x16x32_bf16(al[rf], bh4[cf], acc[rf][cf], 0, 0, 0);
      }
    __syncthreads();
  }

  #pragma unroll
  for (int rf = 0; rf < 2; rf++)
    #pragma unroll
    for (int cf = 0; cf < 4; cf++) {
      const int col = bn + cf * 16 + l15;
      #pragma unroll
      for (int reg = 0; reg < 4; reg++) {
        const int row = bm + wid * 32 + rf * 16 + lk * 4 + reg;
        C[(size_t)row * Ncol + col] = acc[rf][cf][reg];
      }
    }
}

// ---------------------------------------------------------------------------
// Small fp32 GEMM for the N=64 epilogue layers (64x64 tile, 4x4/thread).
// ---------------------------------------------------------------------------
template<int EPI>   // 1 = +bias tanh, 2 = +bias
__global__ __launch_bounds__(256) void gemm_k(
    const float* __restrict__ A, const float* __restrict__ B,
    float* __restrict__ C, const float* __restrict__ bias,
    int M, int Ncol, int K)
{
  __shared__ float As[16][68];
  __shared__ float Bs[16][64];

  const int tid = threadIdx.x;
  const int tx = tid & 15, ty = tid >> 4;
  const int bm = blockIdx.x * 64, bn = blockIdx.y * 64;

  const int arow = tid >> 2;
  const int akc  = (tid & 3) * 4;
  const int brow = tid >> 4;
  const int bc4  = (tid & 15) * 4;

  float acc[4][4];
  #pragma unroll
  for (int i = 0; i < 4; i++)
    #pragma unroll
    for (int j = 0; j < 4; j++) acc[i][j] = 0.f;

  for (int k0 = 0; k0 < K; k0 += 16) {
    const float4 va = *(const float4*)(A + (size_t)(bm + arow) * K + (k0 + akc));
    const float4 vb = *(const float4*)(B + (size_t)(k0 + brow) * Ncol + (bn + bc4));
    As[akc + 0][arow] = va.x; As[akc + 1][arow] = va.y;
    As[akc + 2][arow] = va.z; As[akc + 3][arow] = va.w;
    *(float4*)&Bs[brow][bc4] = vb;
    __syncthreads();
    #pragma unroll
    for (int kk = 0; kk < 16; kk++) {
      const float4 av = *(const float4*)&As[kk][ty * 4];
      const float4 bv = *(const float4*)&Bs[kk][tx * 4];
      const float a4[4] = {av.x, av.y, av.z, av.w};
      const float b4[4] = {bv.x, bv.y, bv.z, bv.w};
      #pragma unroll
      for (int i = 0; i < 4; i++)
        #pragma unroll
        for (int j = 0; j < 4; j++)
          acc[i][j] = fmaf(a4[i], b4[j], acc[i][j]);
    }
    __syncthreads();
  }

  #pragma unroll
  for (int i = 0; i < 4; i++) {
    const int row = bm + ty * 4 + i;
    const int col = bn + tx * 4;
    float v[4] = {acc[i][0], acc[i][1], acc[i][2], acc[i][3]};
    #pragma unroll
    for (int j = 0; j < 4; j++) v[j] += bias[col + j];
    if (EPI == 1) {
      #pragma unroll
      for (int j = 0; j < 4; j++) v[j] = tanhf(v[j]);
    }
    *(float4*)(C + (size_t)row * Ncol + col) = make_float4(v[0], v[1], v[2], v[3]);
  }
}

// ---------------------------------------------------------------------------
// GATv2 aggregation, HC=256 (cout=64): 1 wave per node, 4 nodes/block.
// Lane l owns channels [4l,4l+4); 16-lane group = head. Edges via padded
// es16 table (uint4/batch). Online batch softmax, batch 0 peeled; scores in
// log2 domain. 32-bit gather offsets, SGPR gl base (t block-uniform).
// WF32: also write fp32 out. Always writes bf16 hi/lo split.
// ---------------------------------------------------------------------------
template<bool CONCAT, bool WF32>
__global__ __launch_bounds__(256) void gat_agg256(
    const float* __restrict__ GL, const float* __restrict__ GR,
    const float* __restrict__ aw_, const float* __restrict__ bias,
    const uint* __restrict__ es16, float* __restrict__ out,
    const float* __restrict__ csrc,
    ushort* __restrict__ SHo, ushort* __restrict__ SLo)
{
  constexpr int C = 64;
  constexpr int OSTR = CONCAT ? 128 : 64;

  const int lane = threadIdx.x & 63;
  const int wid  = threadIdx.x >> 6;
  const int t    = blockIdx.x >> 11;          // 2048 blocks per timestep
  const int gid  = blockIdx.x * 4 + wid;

  const float* __restrict__ gl = GL + (size_t)t * N_ * 256;
  const uint*  __restrict__ ep = es16 + (size_t)gid * 16;
  const uint lo16 = (uint)lane << 4;          // lane*16 bytes

  float gr[4], a6[4], a4c[4];
  {
    const float4 gv = *(const float4*)(GR + (size_t)gid * 256 + lane * 4);
    const float4 av = *(const float4*)(aw_ + lane * 4);
    gr[0] = gv.x; gr[1] = gv.y; gr[2] = gv.z; gr[3] = gv.w;
    a6[0] = 0.6f * L2E_ * av.x; a6[1] = 0.6f * L2E_ * av.y;
    a6[2] = 0.6f * L2E_ * av.z; a6[3] = 0.6f * L2E_ * av.w;
    a4c[0] = 0.4f * L2E_ * av.x; a4c[1] = 0.4f * L2E_ * av.y;
    a4c[2] = 0.4f * L2E_ * av.z; a4c[3] = 0.4f * L2E_ * av.w;
  }

  float acc[4] = {0.f, 0.f, 0.f, 0.f};
  float den = 0.f, m = 0.f;

  #pragma unroll
  for (int b = 0; b < 4; b++) {
    const uint4 j4 = *(const uint4*)(ep + b * 4);
    uint off[4];
    off[0] = (j4.x << 10) + lo16;
    off[1] = (j4.y << 10) + lo16;
    off[2] = (j4.z << 10) + lo16;
    off[3] = (j4.w << 10) + lo16;
    float g[4][4];
    #pragma unroll
    for (int q = 0; q < 4; q++) {
      const float4 v = *(const float4*)((const char*)gl + off[q]);
      g[q][0] = v.x; g[q][1] = v.y; g[q][2] = v.z; g[q][3] = v.w;
    }
    float p[4];
    #pragma unroll
    for (int q = 0; q < 4; q++) {
      float s = 0.f;
      #pragma unroll
      for (int u = 0; u < 4; u++) {
        const float z = g[q][u] + gr[u];
        s = fmaf(z, a6[u], s);
        s = fmaf(fabsf(z), a4c[u], s);
      }
      p[q] = s;
    }
    #pragma unroll
    for (int q = 0; q < 4; q++) p[q] = row_reduce16(p[q]);

    const float bmax = fmaxf(fmaxf(p[0], p[1]), fmaxf(p[2], p[3]));
    if (b == 0) {
      m = bmax;
    } else {
      const float nm = fmaxf(m, bmax);
      const float sc = exp2f(m - nm);
      den *= sc;
      #pragma unroll
      for (int u = 0; u < 4; u++) acc[u] *= sc;
      m = nm;
    }
    #pragma unroll
    for (int q = 0; q < 4; q++) {
      const float w = exp2f(p[q] - m);
      den += w;
      #pragma unroll
      for (int u = 0; u < 4; u++) acc[u] = fmaf(w, g[q][u], acc[u]);
    }
  }

  const float inv = 0.25f / den;          // per-head normalizer * head-mean
  #pragma unroll
  for (int u = 0; u < 4; u++) acc[u] *= inv;
  #pragma unroll
  for (int u = 0; u < 4; u++) {
    acc[u] += __shfl_xor(acc[u], 16);
    acc[u] += __shfl_xor(acc[u], 32);
  }

  if (lane < 16) {
    float o[4];
    #pragma unroll
    for (int u = 0; u < 4; u++)
      o[u] = elu1(acc[u] + bias[lane * 4 + u]);
    if (WF32)
      *(float4*)(out + (size_t)gid * OSTR + lane * 4) = make_float4(o[0], o[1], o[2], o[3]);
    ushort4 hh, ll;
    hh.x = f2bf(o[0]); hh.y = f2bf(o[1]); hh.z = f2bf(o[2]); hh.w = f2bf(o[3]);
    ll.x = f2bf(o[0] - bf2f(hh.x)); ll.y = f2bf(o[1] - bf2f(hh.y));
    ll.z = f2bf(o[2] - bf2f(hh.z)); ll.w = f2bf(o[3] - bf2f(hh.w));
    *(ushort4*)(SHo + (size_t)gid * OSTR + lane * 4) = hh;
    *(ushort4*)(SLo + (size_t)gid * OSTR + lane * 4) = ll;
  } else if (CONCAT && lane < 32) {
    const int q = lane - 16;
    const float4 v = *(const float4*)(csrc + (size_t)gid * C + q * 4);
    const float o0 = elu1(v.x), o1 = elu1(v.y), o2 = elu1(v.z), o3 = elu1(v.w);
    if (WF32)
      *(float4*)(out + (size_t)gid * OSTR + C + q * 4) = make_float4(o0, o1, o2, o3);
    ushort4 hh, ll;
    hh.x = f2bf(o0); hh.y = f2bf(o1); hh.z = f2bf(o2); hh.w = f2bf(o3);
    ll.x = f2bf(o0 - bf2f(hh.x)); ll.y = f2bf(o1 - bf2f(hh.y));
    ll.z = f2bf(o2 - bf2f(hh.z)); ll.w = f2bf(o3 - bf2f(hh.w));
    *(ushort4*)(SHo + (size_t)gid * OSTR + C + q * 4) = hh;
    *(ushort4*)(SLo + (size_t)gid * OSTR + C + q * 4) = ll;
  }
}

// ---------------------------------------------------------------------------
// GATv2 aggregation, HC=512 (cout=128): NEW 1 wave per node, 4 nodes/block.
// 16-lane group = head (8 ch/lane covers the head's 128). Same flow as
// agg256: batched loads, 4-DPP reduce per edge, online batch softmax
// (peeled), accumulate from resident g. No LDS, no syncthreads.
// Cross-head mean via shfl 16/32 of per-head-normalized acc.
// ---------------------------------------------------------------------------
template<bool WF32, bool SPLIT>
__global__ __launch_bounds__(256) void gat_agg512(
    const float* __restrict__ GL, const float* __restrict__ GR,
    const float* __restrict__ aw_, const float* __restrict__ bias,
    const uint* __restrict__ es16, float* __restrict__ out,
    ushort* __restrict__ SHo, ushort* __restrict__ SLo)
{
  const int lane = threadIdx.x & 63;
  const int wid  = threadIdx.x >> 6;
  const int t    = blockIdx.x >> 11;          // 2048 blocks per timestep
  const int gid  = blockIdx.x * 4 + wid;

  const float* __restrict__ gl = GL + (size_t)t * N_ * 512;
  const uint*  __restrict__ ep = es16 + (size_t)gid * 16;

  const int s  = lane & 15;
  const int cb = ((lane >> 4) << 7) + (s << 3);   // h*128 + s*8
  const uint laneoff = (uint)cb << 2;             // byte offset within 2048B row

  float gr[8], a6[8], a4[8];
  {
    const float4 g0 = *(const float4*)(GR + (size_t)gid * 512 + cb);
    const float4 g1 = *(const float4*)(GR + (size_t)gid * 512 + cb + 4);
    const float4 a0 = *(const float4*)(aw_ + cb);
    const float4 a1 = *(const float4*)(aw_ + cb + 4);
    gr[0] = g0.x; gr[1] = g0.y; gr[2] = g0.z; gr[3] = g0.w;
    gr[4] = g1.x; gr[5] = g1.y; gr[6] = g1.z; gr[7] = g1.w;
    a6[0] = 0.6f * L2E_ * a0.x; a6[1] = 0.6f * L2E_ * a0.y;
    a6[2] = 0.6f * L2E_ * a0.z; a6[3] = 0.6f * L2E_ * a0.w;
    a6[4] = 0.6f * L2E_ * a1.x; a6[5] = 0.6f * L2E_ * a1.y;
    a6[6] = 0.6f * L2E_ * a1.z; a6[7] = 0.6f * L2E_ * a1.w;
    a4[0] = 0.4f * L2E_ * a0.x; a4[1] = 0.4f * L2E_ * a0.y;
    a4[2] = 0.4f * L2E_ * a0.z; a4[3] = 0.4f * L2E_ * a0.w;
    a4[4] = 0.4f * L2E_ * a1.x; a4[5] = 0.4f * L2E_ * a1.y;
    a4[6] = 0.4f * L2E_ * a1.z; a4[7] = 0.4f * L2E_ * a1.w;
  }

  float acc[8] = {0.f, 0.f, 0.f, 0.f, 0.f, 0.f, 0.f, 0.f};
  float den = 0.f, m = 0.f;

  #pragma unroll
  for (int b = 0; b < 4; b++) {
    const uint4 j4 = *(const uint4*)(ep + b * 4);
    uint off[4];
    off[0] = (j4.x << 11) + laneoff;
    off[1] = (j4.y << 11) + laneoff;
    off[2] = (j4.z << 11) + laneoff;
    off[3] = (j4.w << 11) + laneoff;
    float g[4][8];
    #pragma unroll
    for (int q = 0; q < 4; q++) {
      const float4 v0 = *(const float4*)((const char*)gl + off[q]);
      const float4 v1 = *(const float4*)((const char*)gl + off[q] + 16);
      g[q][0] = v0.x; g[q][1] = v0.y; g[q][2] = v0.z; g[q][3] = v0.w;
      g[q][4] = v1.x; g[q][5] = v1.y; g[q][6] = v1.z; g[q][7] = v1.w;
    }
    float p[4];
    #pragma unroll
    for (int q = 0; q < 4; q++) {
      float sc = 0.f;
      #pragma unroll
      for (int u = 0; u < 8; u++) {
        const float z = g[q][u] + gr[u];
        sc = fmaf(z, a6[u], sc);
        sc = fmaf(fabsf(z), a4[u], sc);
      }
      p[q] = sc;
    }
    #pragma unroll
    for (int q = 0; q < 4; q++) p[q] = row_reduce16(p[q]);

    const float bmax = fmaxf(fmaxf(p[0], p[1]), fmaxf(p[2], p[3]));
    if (b == 0) {
      m = bmax;
    } else {
      const float nm = fmaxf(m, bmax);
      const float sc = exp2f(m - nm);
      den *= sc;
      #pragma unroll
      for (int u = 0; u < 8; u++) acc[u] *= sc;
      m = nm;
    }
    #pragma unroll
    for (int q = 0; q < 4; q++) {
      const float w = exp2f(p[q] - m);
      den += w;
      #pragma unroll
      for (int u = 0; u < 8; u++) acc[u] = fmaf(w, g[q][u], acc[u]);
    }
  }

  const float inv = 0.25f / den;          // per-head normalizer * head-mean
  #pragma unroll
  for (int u = 0; u < 8; u++) acc[u] *= inv;
  #pragma unroll
  for (int u = 0; u < 8; u++) {           // cross-head sum (heads at lanes s+16h)
    acc[u] += __shfl_xor(acc[u], 16);
    acc[u] += __shfl_xor(acc[u], 32);
  }

  if (lane < 16) {
    float o[8];
    #pragma unroll
    for (int u = 0; u < 8; u++)
      o[u] = elu1(acc[u] + bias[s * 8 + u]);
    if (WF32) {
      *(float4*)(out + (size_t)gid * 128 + s * 8)     = make_float4(o[0], o[1], o[2], o[3]);
      *(float4*)(out + (size_t)gid * 128 + s * 8 + 4) = make_float4(o[4], o[5], o[6], o[7]);
    }
    if (SPLIT) {
      ushort4 h0, h1, l0, l1;
      h0.x = f2bf(o[0]); h0.y = f2bf(o[1]); h0.z = f2bf(o[2]); h0.w = f2bf(o[3]);
      h1.x = f2bf(o[4]); h1.y = f2bf(o[5]); h1.z = f2bf(o[6]); h1.w = f2bf(o[7]);
      l0.x = f2bf(o[0] - bf2f(h0.x)); l0.y = f2bf(o[1] - bf2f(h0.y));
      l0.z = f2bf(o[2] - bf2f(h0.z)); l0.w = f2bf(o[3] - bf2f(h0.w));
      l1.x = f2bf(o[4] - bf2f(h1.x)); l1.y = f2bf(o[5] - bf2f(h1.y));
      l1.z = f2bf(o[6] - bf2f(h1.z)); l1.w = f2bf(o[7] - bf2f(h1.w));
      *(ushort4*)(SHo + (size_t)gid * 128 + s * 8)     = h0;
      *(ushort4*)(SHo + (size_t)gid * 128 + s * 8 + 4) = h1;
      *(ushort4*)(SLo + (size_t)gid * 128 + s * 8)     = l0;
      *(ushort4*)(SLo + (size_t)gid * 128 + s * 8 + 4) = l1;
    }
  }
}

// ---------------------------------------------------------------------------
extern "C" void kernel_launch(void* const* d_in, const int* in_sizes, int n_in,
                              void* d_out, int out_size, void* d_ws, size_t ws_size,
                              hipStream_t stream)
{
  (void)in_sizes; (void)n_in; (void)out_size; (void)ws_size;

  const float* x  = (const float*)d_in[0];
  const int*   es = (const int*)d_in[1];
  const float *c1_wl=(const float*)d_in[3], *c1_wr=(const float*)d_in[4], *c1_a=(const float*)d_in[5], *c1_b=(const float*)d_in[6];
  const float *c2_wl=(const float*)d_in[7], *c2_wr=(const float*)d_in[8], *c2_a=(const float*)d_in[9], *c2_b=(const float*)d_in[10];
  const float *c3_wl=(const float*)d_in[11],*c3_wr=(const float*)d_in[12],*c3_a=(const float*)d_in[13],*c3_b=(const float*)d_in[14];
  const float *c4_wl=(const float*)d_in[15],*c4_wr=(const float*)d_in[16],*c4_a=(const float*)d_in[17],*c4_b=(const float*)d_in[18];
  const float *r11_wl=(const float*)d_in[19],*r11_wr=(const float*)d_in[20],*r11_a=(const float*)d_in[21],*r11_b=(const float*)d_in[22];
  const float *r12_wl=(const float*)d_in[23],*r12_wr=(const float*)d_in[24],*r12_a=(const float*)d_in[25],*r12_b=(const float*)d_in[26];
  const float *r2_wl=(const float*)d_in[27],*r2_wr=(const float*)d_in[28],*r2_a=(const float*)d_in[29],*r2_b=(const float*)d_in[30];
  const float *f11_wl=(const float*)d_in[31],*f11_wr=(const float*)d_in[32],*f11_a=(const float*)d_in[33],*f11_b=(const float*)d_in[34];
  const float *f2_wl=(const float*)d_in[35],*f2_wr=(const float*)d_in[36],*f2_a=(const float*)d_in[37],*f2_b=(const float*)d_in[38];
  const float *r3_w=(const float*)d_in[39], *r3_b=(const float*)d_in[40];
  const float *f3_w=(const float*)d_in[41], *f3_b=(const float*)d_in[42];
  const float *r4_w=(const float*)d_in[43], *r4_b=(const float*)d_in[44];
  const float *f4_w=(const float*)d_in[45], *f4_b=(const float*)d_in[46];

  // Workspace layout
  float* ws = (float*)d_ws;
  float* GL = ws;                                       // 16.7M f
  float* GR = GL + (size_t)16777216;                    // 16.7M f
  float* A1 = GR + (size_t)16777216;                    // [T,N,64] emb2 fp32
  float* B0 = A1 + (size_t)T_ * N_ * 64;                // [N,128]
  float* B1 = B0 + (size_t)N_ * 128;                    // [N,128]
  ushort* SH  = (ushort*)(B1 + (size_t)N_ * 128);       // split ping
  ushort* SL  = SH + (size_t)8388608;
  ushort* SH2 = SL + (size_t)8388608;                   // split pong
  ushort* SL2 = SH2 + (size_t)8388608;
  ushort* WH  = SL2 + (size_t)8388608;                  // 589824 u16
  ushort* WL  = WH + (size_t)589824;
  uint*  ES16 = (uint*)(WL + (size_t)589824);           // [T,N,16]

  float* recon = (float*)d_out;
  float* fcst  = recon + (size_t)N_ * 64;
  float* emb   = fcst + (size_t)N_ * 64;        // [T,N,64]

  const dim3 blk(256);

  // ---- one-time prep: padded edges, input split, all weight splits ----
  pad_edges<<<dim3(T_ * N_ / 256), blk, 0, stream>>>(es, ES16, T_ * N_);
  split_x<<<dim3(T_ * N_ * 64 / 4 / 256), blk, 0, stream>>>(x, SH, SL, T_ * N_ * 64 / 4);
  WTable tb;
  const float* wls[9] = {c1_wl, c2_wl, c3_wl, c4_wl, r11_wl, r12_wl, r2_wl, f11_wl, f2_wl};
  const float* wrs[9] = {c1_wr, c2_wr, c3_wr, c4_wr, r11_wr, r12_wr, r2_wr, f11_wr, f2_wr};
  const int Ks[9]  = {64, 128, 64, 128, 64, 64, 128, 64, 128};
  const int HCs[9] = {512, 256, 256, 256, 256, 256, 512, 256, 512};
  int woff[9]; int acc_off = 0;
  for (int y = 0; y < 9; y++) {
    tb.wl[y] = wls[y]; tb.wr[y] = wrs[y];
    tb.lgK[y] = __builtin_ctz(Ks[y]); tb.lgHC[y] = __builtin_ctz(HCs[y]);
    woff[y] = acc_off; tb.off[y] = acc_off;
    acc_off += 2 * Ks[y] * HCs[y];
  }
  split_wt_all<<<dim3(512, 9), blk, 0, stream>>>(tb, WH, WL);

  // ---- c1: 64 -> 128 (HC=512); out consumed only via split -> SH2/SL2 ----
  for (int ch = 0; ch < 2; ch++) {
    const int t0 = ch * 4, nt = 4;
    gemm_mfma<<<dim3(N_ / 128, 8, 2 * nt), blk, 0, stream>>>(
        SH + (size_t)t0 * N_ * 64, SL + (size_t)t0 * N_ * 64,
        WH + woff[0], WL + woff[0], GL, GR, N_, 512, 64, nt);
    gat_agg512<false, true><<<dim3(nt * N_ / 4), blk, 0, stream>>>(
        GL, GR, c1_a, c1_b, ES16 + (size_t)t0 * N_ * 16, nullptr,
        SH2 + (size_t)t0 * N_ * 128, SL2 + (size_t)t0 * N_ * 128);
  }
  // ---- c2: 128 -> 64; emb2 fp32 (concat src) + split -> SH/SL ----
  gemm_mfma<<<dim3(N_ / 128, 4, 2 * T_), blk, 0, stream>>>(
      SH2, SL2, WH + woff[1], WL + woff[1], GL, GR, N_, 256, 128, T_);
  gat_agg256<false, true><<<dim3(T_ * N_ / 4), blk, 0, stream>>>(
      GL, GR, c2_a, c2_b, ES16, A1, nullptr, SH, SL);
  // ---- c3: 64 -> 64, concat elu(emb2); out via split -> SH/SL ----
  gemm_mfma<<<dim3(N_ / 128, 4, 2 * T_), blk, 0, stream>>>(
      SH, SL, WH + woff[2], WL + woff[2], GL, GR, N_, 256, 64, T_);
  gat_agg256<true, false><<<dim3(T_ * N_ / 4), blk, 0, stream>>>(
      GL, GR, c3_a, c3_b, ES16, nullptr, A1, SH, SL);
  // ---- c4: 128 -> 64 -> emb (d_out) + split -> SH2/SL2 ----
  gemm_mfma<<<dim3(N_ / 128, 4, 2 * T_), blk, 0, stream>>>(
      SH, SL, WH + woff[3], WL + woff[3], GL, GR, N_, 256, 128, T_);
  gat_agg256<false, true><<<dim3(T_ * N_ / 4), blk, 0, stream>>>(
      GL, GR, c4_a, c4_b, ES16, emb, nullptr, SH2, SL2);

  // ---- reconstruction branch (edges at t = 7; emb split slice 7) ----
  const uint* esR = ES16 + (size_t)7 * N_ * 16;
  gemm_mfma<<<dim3(N_ / 128, 4, 2), blk, 0, stream>>>(
      SH2 + (size_t)7 * N_ * 64, SL2 + (size_t)7 * N_ * 64,
      WH + woff[4], WL + woff[4], GL, GR, N_, 256, 64, 1);
  gat_agg256<false, true><<<dim3(N_ / 4), blk, 0, stream>>>(
      GL, GR, r11_a, r11_b, esR, B0, nullptr, SH, SL);
  gemm_mfma<<<dim3(N_ / 128, 4, 2), blk, 0, stream>>>(
      SH, SL, WH + woff[5], WL + woff[5], GL, GR, N_, 256, 64, 1);
  gat_agg256<true, false><<<dim3(N_ / 4), blk, 0, stream>>>(
      GL, GR, r12_a, r12_b, esR, nullptr, B0, SH, SL);
  gemm_mfma<<<dim3(N_ / 128, 8, 2), blk, 0, stream>>>(
      SH, SL, WH + woff[6], WL + woff[6], GL, GR, N_, 512, 128, 1);
  gat_agg512<true, false><<<dim3(N_ / 4), blk, 0, stream>>>(
      GL, GR, r2_a, r2_b, esR, B0, nullptr, nullptr);
  gemm_k<1><<<dim3(N_ / 64, 1, 1), blk, 0, stream>>>(B0, r3_w, B1, r3_b, N_, 64, 128);
  gemm_k<2><<<dim3(N_ / 64, 1, 1), blk, 0, stream>>>(B1, r4_w, recon, r4_b, N_, 64, 64);

  // ---- forecasting branch (edges at t = 6; emb split slice 6) ----
  const uint* esF = ES16 + (size_t)6 * N_ * 16;
  gemm_mfma<<<dim3(N_ / 128, 4, 2), blk, 0, stream>>>(
      SH2 + (size_t)6 * N_ * 64, SL2 + (size_t)6 * N_ * 64,
      WH + woff[7], WL + woff[7], GL, GR, N_, 256, 64, 1);
  gat_agg256<false, true><<<dim3(N_ / 4), blk, 0, stream>>>(
      GL, GR, f11_a, f11_b, esF, B0, nullptr, SH, SL);
  gemm_mfma<<<dim3(N_ / 128, 4, 2), blk, 0, stream>>>(
      SH, SL, WH + woff[5], WL + woff[5], GL, GR, N_, 256, 64, 1);
  gat_agg256<true, false><<<dim3(N_ / 4), blk, 0, stream>>>(
      GL, GR, r12_a, r12_b, esF, nullptr, B0, SH, SL);
  gemm_mfma<<<dim3(N_ / 128, 8, 2), blk, 0, stream>>>(
      SH, SL, WH + woff[8], WL + woff[8], GL, GR, N_, 512, 128, 1);
  gat_agg512<true, false><<<dim3(N_ / 4), blk, 0, stream>>>(
      GL, GR, f2_a, f2_b, esF, B0, nullptr, nullptr);
  gemm_k<1><<<dim3(N_ / 64, 1, 1), blk, 0, stream>>>(B0, f3_w, B1, f3_b, N_, 64, 128);
  gemm_k<2><<<dim3(N_ / 64, 1, 1), blk, 0, stream>>>(B1, f4_w, fcst, f4_b, N_, 64, 64);
}

// Round 11
// 957.074 us; speedup vs baseline: 1.4710x; 1.0464x over previous
//
#include <hip/hip_runtime.h>
#include <cmath>

// Problem constants (from reference setup_inputs)
constexpr int T_   = 8;
constexpr int N_   = 8192;
constexpr int DEG_ = 15;
constexpr int E_   = N_ * (DEG_ + 1);   // 131072 edges per timestep
constexpr float L2E_ = 1.44269504f;

// fast ELU: expm1 via exp2 (abs err ~1e-7, threshold 7e-4)
__device__ __forceinline__ float elu1(float v) {
  return v > 0.f ? v : exp2f(v * L2E_) - 1.f;
}

typedef __attribute__((ext_vector_type(8))) short bf16x8;
typedef __attribute__((ext_vector_type(4))) float f32x4;

__device__ __forceinline__ ushort f2bf(float x) {
  uint u = __float_as_uint(x);
  return (ushort)((u + 0x7FFFu + ((u >> 16) & 1u)) >> 16);
}
__device__ __forceinline__ float bf2f(ushort h) {
  return __uint_as_float(((uint)h) << 16);
}

// v_add with DPP row_ror: sum over each 16-lane row after steps 1,2,4,8.
template<int CTRL>
__device__ __forceinline__ float dpp_add(float x) {
  const int t = __builtin_amdgcn_mov_dpp(__float_as_int(x), CTRL, 0xf, 0xf, true);
  return x + __int_as_float(t);
}
__device__ __forceinline__ float row_reduce16(float x) {
  x = dpp_add<0x121>(x);   // row_ror:1
  x = dpp_add<0x122>(x);   // row_ror:2
  x = dpp_add<0x124>(x);   // row_ror:4
  x = dpp_add<0x128>(x);   // row_ror:8
  return x;
}

// ---------------------------------------------------------------------------
// pad_edges: es[T][N*DEG] -> es16[T][N][16] (15 edges + self loop), uint.
// ---------------------------------------------------------------------------
__global__ __launch_bounds__(256) void pad_edges(
    const int* __restrict__ es, uint* __restrict__ es16, int total)
{
  const int idx = blockIdx.x * 256 + threadIdx.x;
  if (idx >= total) return;
  const int t = idx >> 13, i = idx & (N_ - 1);
  const int* e = es + (size_t)t * E_ + (size_t)i * DEG_;
  uint o[16];
  #pragma unroll
  for (int k = 0; k < DEG_; k++) o[k] = (uint)e[k];
  o[15] = (uint)i;
  uint4* dst = (uint4*)(es16 + (size_t)idx * 16);
  dst[0] = make_uint4(o[0], o[1], o[2], o[3]);
  dst[1] = make_uint4(o[4], o[5], o[6], o[7]);
  dst[2] = make_uint4(o[8], o[9], o[10], o[11]);
  dst[3] = make_uint4(o[12], o[13], o[14], o[15]);
}

// ---------------------------------------------------------------------------
// split_x: fp32 array -> hi/lo bf16 arrays (same layout). 4 elems/thread.
// ---------------------------------------------------------------------------
__global__ __launch_bounds__(256) void split_x(
    const float* __restrict__ X, ushort* __restrict__ XH, ushort* __restrict__ XL, int n4)
{
  const int i = blockIdx.x * 256 + threadIdx.x;
  if (i >= n4) return;
  const float4 v = ((const float4*)X)[i];
  const ushort h0 = f2bf(v.x), h1 = f2bf(v.y), h2 = f2bf(v.z), h3 = f2bf(v.w);
  ushort4 hh; hh.x = h0; hh.y = h1; hh.z = h2; hh.w = h3;
  ushort4 ll;
  ll.x = f2bf(v.x - bf2f(h0)); ll.y = f2bf(v.y - bf2f(h1));
  ll.z = f2bf(v.z - bf2f(h2)); ll.w = f2bf(v.w - bf2f(h3));
  ((ushort4*)XH)[i] = hh;
  ((ushort4*)XL)[i] = ll;
}

// ---------------------------------------------------------------------------
// split_wt_all: all 9 weight pairs in one launch. grid.y = pair index.
// ---------------------------------------------------------------------------
struct WTable {
  const float* wl[9]; const float* wr[9];
  int lgK[9]; int lgHC[9]; int off[9];
};
__global__ __launch_bounds__(256) void split_wt_all(
    WTable tb, ushort* __restrict__ WH, ushort* __restrict__ WL)
{
  const int y = blockIdx.y;
  const int lgK = tb.lgK[y], lgHC = tb.lgHC[y];
  const int n2 = 2 << (lgK + lgHC);
  const int idx = blockIdx.x * 256 + threadIdx.x;
  if (idx >= n2) return;
  const int k = idx & ((1 << lgK) - 1);
  const int n = (idx >> lgK) & ((1 << lgHC) - 1);
  const int s = idx >> (lgK + lgHC);
  const float* W = s ? tb.wr[y] : tb.wl[y];
  const float v = W[((size_t)k << lgHC) + n];
  const ushort h = f2bf(v);
  WH[tb.off[y] + idx] = h;
  WL[tb.off[y] + idx] = f2bf(v - bf2f(h));
}

// ---------------------------------------------------------------------------
// MFMA GEMM (split-bf16): C = A @ W, A hi/lo [nt][M][K] bf16, W hi/lo
// [2][Ncol][K] bf16 (transposed). x.w ~= ah.wh + ah.wl + al.wh.
// BM=128, BN=64, BK=32; 256 thr = 4 waves.
// ---------------------------------------------------------------------------
__global__ __launch_bounds__(256) void gemm_mfma(
    const ushort* __restrict__ Ah, const ushort* __restrict__ Al,
    const ushort* __restrict__ Wh, const ushort* __restrict__ Wl,
    float* __restrict__ Cl, float* __restrict__ Cr,
    int M, int Ncol, int K, int nt)
{
  __shared__ alignas(16) ushort lAh[4 * 1032];
  __shared__ alignas(16) ushort lAl[4 * 1032];
  __shared__ alignas(16) ushort lBh[4 * 520];
  __shared__ alignas(16) ushort lBl[4 * 520];

  const int z = blockIdx.z;
  const int t = (z < nt) ? z : z - nt;
  const int side = (z < nt) ? 0 : 1;
  const ushort* __restrict__ Bh = Wh + (size_t)side * Ncol * K;
  const ushort* __restrict__ Bl = Wl + (size_t)side * Ncol * K;
  float* __restrict__ C = (side ? Cr : Cl) + (size_t)t * M * Ncol;
  const size_t aoff = (size_t)t * M * K;

  const int bm = blockIdx.x * 128, bn = blockIdx.y * 64;
  const int tid = threadIdx.x;
  const int wid = tid >> 6, lane = tid & 63;
  const int l15 = lane & 15, lk = lane >> 4;

  f32x4 acc[2][4] = {};

  for (int k0 = 0; k0 < K; k0 += 32) {
    #pragma unroll
    for (int c = 0; c < 2; c++) {
      const int ch = tid + c * 256;
      const int row = ch >> 2, kc = ch & 3;
      const size_t ga = aoff + (size_t)(bm + row) * K + (k0 + kc * 8);
      *(uint4*)&lAh[kc * 1032 + row * 8] = *(const uint4*)(Ah + ga);
      *(uint4*)&lAl[kc * 1032 + row * 8] = *(const uint4*)(Al + ga);
    }
    {
      const int col = tid >> 2, kc = tid & 3;
      const size_t gb = (size_t)(bn + col) * K + (k0 + kc * 8);
      *(uint4*)&lBh[kc * 520 + col * 8] = *(const uint4*)(Bh + gb);
      *(uint4*)&lBl[kc * 520 + col * 8] = *(const uint4*)(Bl + gb);
    }
    __syncthreads();

    bf16x8 ah[2], al[2], bh4[4], bl4[4];
    const int r0 = wid * 32;
    #pragma unroll
    for (int rf = 0; rf < 2; rf++) {
      const int ro = (r0 + rf * 16 + l15) * 8;
      ah[rf] = *(const bf16x8*)&lAh[lk * 1032 + ro];
      al[rf] = *(const bf16x8*)&lAl[lk * 1032 + ro];
    }
    #pragma unroll
    for (int cf = 0; cf < 4; cf++) {
      const int co = (cf * 16 + l15) * 8;
      bh4[cf] = *(const bf16x8*)&lBh[lk * 520 + co];
      bl4[cf] = *(const bf16x8*)&lBl[lk * 520 + co];
    }
    #pragma unroll
    for (int rf = 0; rf < 2; rf++)
      #pragma unroll
      for (int cf = 0; cf < 4; cf++) {
        acc[rf][cf] = __builtin_amdgcn_mfma_f32_16x16x32_bf16(ah[rf], bh4[cf], acc[rf][cf], 0, 0, 0);
        acc[rf][cf] = __builtin_amdgcn_mfma_f32_16x16x32_bf16(ah[rf], bl4[cf], acc[rf][cf], 0, 0, 0);
        acc[rf][cf] = __builtin_amdgcn_mfma_f32_16x16x32_bf16(al[rf], bh4[cf], acc[rf][cf], 0, 0, 0);
      }
    __syncthreads();
  }

  #pragma unroll
  for (int rf = 0; rf < 2; rf++)
    #pragma unroll
    for (int cf = 0; cf < 4; cf++) {
      const int col = bn + cf * 16 + l15;
      #pragma unroll
      for (int reg = 0; reg < 4; reg++) {
        const int row = bm + wid * 32 + rf * 16 + lk * 4 + reg;
        C[(size_t)row * Ncol + col] = acc[rf][cf][reg];
      }
    }
}

// ---------------------------------------------------------------------------
// Small fp32 GEMM for the N=64 epilogue layers (64x64 tile, 4x4/thread).
// ---------------------------------------------------------------------------
template<int EPI>   // 1 = +bias tanh, 2 = +bias
__global__ __launch_bounds__(256) void gemm_k(
    const float* __restrict__ A, const float* __restrict__ B,
    float* __restrict__ C, const float* __restrict__ bias,
    int M, int Ncol, int K)
{
  __shared__ float As[16][68];
  __shared__ float Bs[16][64];

  const int tid = threadIdx.x;
  const int tx = tid & 15, ty = tid >> 4;
  const int bm = blockIdx.x * 64, bn = blockIdx.y * 64;

  const int arow = tid >> 2;
  const int akc  = (tid & 3) * 4;
  const int brow = tid >> 4;
  const int bc4  = (tid & 15) * 4;

  float acc[4][4];
  #pragma unroll
  for (int i = 0; i < 4; i++)
    #pragma unroll
    for (int j = 0; j < 4; j++) acc[i][j] = 0.f;

  for (int k0 = 0; k0 < K; k0 += 16) {
    const float4 va = *(const float4*)(A + (size_t)(bm + arow) * K + (k0 + akc));
    const float4 vb = *(const float4*)(B + (size_t)(k0 + brow) * Ncol + (bn + bc4));
    As[akc + 0][arow] = va.x; As[akc + 1][arow] = va.y;
    As[akc + 2][arow] = va.z; As[akc + 3][arow] = va.w;
    *(float4*)&Bs[brow][bc4] = vb;
    __syncthreads();
    #pragma unroll
    for (int kk = 0; kk < 16; kk++) {
      const float4 av = *(const float4*)&As[kk][ty * 4];
      const float4 bv = *(const float4*)&Bs[kk][tx * 4];
      const float a4[4] = {av.x, av.y, av.z, av.w};
      const float b4[4] = {bv.x, bv.y, bv.z, bv.w};
      #pragma unroll
      for (int i = 0; i < 4; i++)
        #pragma unroll
        for (int j = 0; j < 4; j++)
          acc[i][j] = fmaf(a4[i], b4[j], acc[i][j]);
    }
    __syncthreads();
  }

  #pragma unroll
  for (int i = 0; i < 4; i++) {
    const int row = bm + ty * 4 + i;
    const int col = bn + tx * 4;
    float v[4] = {acc[i][0], acc[i][1], acc[i][2], acc[i][3]};
    #pragma unroll
    for (int j = 0; j < 4; j++) v[j] += bias[col + j];
    if (EPI == 1) {
      #pragma unroll
      for (int j = 0; j < 4; j++) v[j] = tanhf(v[j]);
    }
    *(float4*)(C + (size_t)row * Ncol + col) = make_float4(v[0], v[1], v[2], v[3]);
  }
}

// ---------------------------------------------------------------------------
// GATv2 aggregation, HC=256 (cout=64): 1 wave per node, 4 nodes/block.
// SWZ: XCD-aware swizzle — timestep t pinned to XCD t (t = bid & 7) so each
// XCD's 4MB L2 caches one timestep's 8MB GL slice instead of all 64MB.
// ---------------------------------------------------------------------------
template<bool SWZ, bool CONCAT, bool WF32>
__global__ __launch_bounds__(256) void gat_agg256(
    const float* __restrict__ GL, const float* __restrict__ GR,
    const float* __restrict__ aw_, const float* __restrict__ bias,
    const uint* __restrict__ es16, float* __restrict__ out,
    const float* __restrict__ csrc,
    ushort* __restrict__ SHo, ushort* __restrict__ SLo)
{
  constexpr int C = 64;
  constexpr int OSTR = CONCAT ? 128 : 64;

  const int lane = threadIdx.x & 63;
  const int wid  = threadIdx.x >> 6;
  const int bid  = blockIdx.x;
  const int t    = SWZ ? (bid & 7) : 0;
  const int ib   = SWZ ? (bid >> 3) : bid;    // block index within timestep
  const int gid  = t * N_ + ib * 4 + wid;

  const float* __restrict__ gl = GL + (size_t)t * N_ * 256;
  const uint*  __restrict__ ep = es16 + (size_t)gid * 16;
  const uint lo16 = (uint)lane << 4;          // lane*16 bytes

  float gr[4], a6[4], a4c[4];
  {
    const float4 gv = *(const float4*)(GR + (size_t)gid * 256 + lane * 4);
    const float4 av = *(const float4*)(aw_ + lane * 4);
    gr[0] = gv.x; gr[1] = gv.y; gr[2] = gv.z; gr[3] = gv.w;
    a6[0] = 0.6f * L2E_ * av.x; a6[1] = 0.6f * L2E_ * av.y;
    a6[2] = 0.6f * L2E_ * av.z; a6[3] = 0.6f * L2E_ * av.w;
    a4c[0] = 0.4f * L2E_ * av.x; a4c[1] = 0.4f * L2E_ * av.y;
    a4c[2] = 0.4f * L2E_ * av.z; a4c[3] = 0.4f * L2E_ * av.w;
  }

  float acc[4] = {0.f, 0.f, 0.f, 0.f};
  float den = 0.f, m = 0.f;

  #pragma unroll
  for (int b = 0; b < 4; b++) {
    const uint4 j4 = *(const uint4*)(ep + b * 4);
    uint off[4];
    off[0] = (j4.x << 10) + lo16;
    off[1] = (j4.y << 10) + lo16;
    off[2] = (j4.z << 10) + lo16;
    off[3] = (j4.w << 10) + lo16;
    float g[4][4];
    #pragma unroll
    for (int q = 0; q < 4; q++) {
      const float4 v = *(const float4*)((const char*)gl + off[q]);
      g[q][0] = v.x; g[q][1] = v.y; g[q][2] = v.z; g[q][3] = v.w;
    }
    float p[4];
    #pragma unroll
    for (int q = 0; q < 4; q++) {
      float s = 0.f;
      #pragma unroll
      for (int u = 0; u < 4; u++) {
        const float z = g[q][u] + gr[u];
        s = fmaf(z, a6[u], s);
        s = fmaf(fabsf(z), a4c[u], s);
      }
      p[q] = s;
    }
    #pragma unroll
    for (int q = 0; q < 4; q++) p[q] = row_reduce16(p[q]);

    const float bmax = fmaxf(fmaxf(p[0], p[1]), fmaxf(p[2], p[3]));
    if (b == 0) {
      m = bmax;
    } else {
      const float nm = fmaxf(m, bmax);
      const float sc = exp2f(m - nm);
      den *= sc;
      #pragma unroll
      for (int u = 0; u < 4; u++) acc[u] *= sc;
      m = nm;
    }
    #pragma unroll
    for (int q = 0; q < 4; q++) {
      const float w = exp2f(p[q] - m);
      den += w;
      #pragma unroll
      for (int u = 0; u < 4; u++) acc[u] = fmaf(w, g[q][u], acc[u]);
    }
  }

  const float inv = 0.25f / den;          // per-head normalizer * head-mean
  #pragma unroll
  for (int u = 0; u < 4; u++) acc[u] *= inv;
  #pragma unroll
  for (int u = 0; u < 4; u++) {
    acc[u] += __shfl_xor(acc[u], 16);
    acc[u] += __shfl_xor(acc[u], 32);
  }

  if (lane < 16) {
    float o[4];
    #pragma unroll
    for (int u = 0; u < 4; u++)
      o[u] = elu1(acc[u] + bias[lane * 4 + u]);
    if (WF32)
      *(float4*)(out + (size_t)gid * OSTR + lane * 4) = make_float4(o[0], o[1], o[2], o[3]);
    ushort4 hh, ll;
    hh.x = f2bf(o[0]); hh.y = f2bf(o[1]); hh.z = f2bf(o[2]); hh.w = f2bf(o[3]);
    ll.x = f2bf(o[0] - bf2f(hh.x)); ll.y = f2bf(o[1] - bf2f(hh.y));
    ll.z = f2bf(o[2] - bf2f(hh.z)); ll.w = f2bf(o[3] - bf2f(hh.w));
    *(ushort4*)(SHo + (size_t)gid * OSTR + lane * 4) = hh;
    *(ushort4*)(SLo + (size_t)gid * OSTR + lane * 4) = ll;
  } else if (CONCAT && lane < 32) {
    const int q = lane - 16;
    const float4 v = *(const float4*)(csrc + (size_t)gid * C + q * 4);
    const float o0 = elu1(v.x), o1 = elu1(v.y), o2 = elu1(v.z), o3 = elu1(v.w);
    if (WF32)
      *(float4*)(out + (size_t)gid * OSTR + C + q * 4) = make_float4(o0, o1, o2, o3);
    ushort4 hh, ll;
    hh.x = f2bf(o0); hh.y = f2bf(o1); hh.z = f2bf(o2); hh.w = f2bf(o3);
    ll.x = f2bf(o0 - bf2f(hh.x)); ll.y = f2bf(o1 - bf2f(hh.y));
    ll.z = f2bf(o2 - bf2f(hh.z)); ll.w = f2bf(o3 - bf2f(hh.w));
    *(ushort4*)(SHo + (size_t)gid * OSTR + C + q * 4) = hh;
    *(ushort4*)(SLo + (size_t)gid * OSTR + C + q * 4) = ll;
  }
}

// ---------------------------------------------------------------------------
// GATv2 aggregation, HC=512 (cout=128): REVERT to r9 shape (24 VGPR, 84%
// VALU): 1 node per block, 1 head per wave, lane owns 2 ch. Padded edge
// table + peeled batch-0 kept from r10. SWZ (c1 chunks, nt=4): 2 XCDs per
// timestep (t = (bid&7)>>1) to localize the 16MB/t GL slice.
// ---------------------------------------------------------------------------
template<bool SWZ, bool WF32, bool SPLIT>
__global__ __launch_bounds__(256) void gat_agg512(
    const float* __restrict__ GL, const float* __restrict__ GR,
    const float* __restrict__ aw_, const float* __restrict__ bias,
    const uint* __restrict__ es16, float* __restrict__ out,
    ushort* __restrict__ SHo, ushort* __restrict__ SLo)
{
  __shared__ float smem[4][128];

  const int lane = threadIdx.x & 63;
  const int h    = threadIdx.x >> 6;
  const int bid  = blockIdx.x;
  int t, i;
  if (SWZ) {                 // nt=4 chunk: bid in [0, 32768)
    const int xcd = bid & 7;
    t = xcd >> 1;
    i = ((bid >> 3) << 1) | (xcd & 1);   // [0, 8192)
  } else {                   // nt=1: bid in [0, 8192)
    t = 0; i = bid;
  }
  const int gid = t * N_ + i;

  const float* __restrict__ gl = GL + (size_t)t * N_ * 512;
  const uint*  __restrict__ ep = es16 + (size_t)gid * 16;
  const int cb = h * 128 + lane * 2;
  const uint cbo = (uint)cb << 2;             // byte offset within 2048B row

  float gr0, gr1, a60, a61, a40, a41;
  {
    const float2 gv = *(const float2*)(GR + (size_t)gid * 512 + cb);
    const float2 av = *(const float2*)(aw_ + cb);
    gr0 = gv.x; gr1 = gv.y;
    a60 = 0.6f * L2E_ * av.x; a61 = 0.6f * L2E_ * av.y;
    a40 = 0.4f * L2E_ * av.x; a41 = 0.4f * L2E_ * av.y;
  }

  float acc0 = 0.f, acc1 = 0.f, den = 0.f, m = 0.f;

  #pragma unroll
  for (int b = 0; b < 4; b++) {
    const uint4 j4 = *(const uint4*)(ep + b * 4);
    uint off[4];
    off[0] = (j4.x << 11) + cbo;
    off[1] = (j4.y << 11) + cbo;
    off[2] = (j4.z << 11) + cbo;
    off[3] = (j4.w << 11) + cbo;
    float g[4][2];
    #pragma unroll
    for (int q = 0; q < 4; q++) {
      const float2 v = *(const float2*)((const char*)gl + off[q]);
      g[q][0] = v.x; g[q][1] = v.y;
    }
    float p[4];
    #pragma unroll
    for (int q = 0; q < 4; q++) {
      const float z0 = g[q][0] + gr0;
      const float z1 = g[q][1] + gr1;
      float s = z0 * a60;
      s = fmaf(fabsf(z0), a40, s);
      s = fmaf(z1, a61, s);
      s = fmaf(fabsf(z1), a41, s);
      p[q] = s;
    }
    #pragma unroll
    for (int q = 0; q < 4; q++) {     // full-wave reduce (64 lanes = 1 head)
      p[q] = row_reduce16(p[q]);
      p[q] += __shfl_xor(p[q], 16);
      p[q] += __shfl_xor(p[q], 32);
    }
    const float bmax = fmaxf(fmaxf(p[0], p[1]), fmaxf(p[2], p[3]));
    if (b == 0) {
      m = bmax;
    } else {
      const float nm = fmaxf(m, bmax);
      const float sc = exp2f(m - nm);
      den *= sc; acc0 *= sc; acc1 *= sc;
      m = nm;
    }
    #pragma unroll
    for (int q = 0; q < 4; q++) {
      const float w = exp2f(p[q] - m);
      den += w;
      acc0 = fmaf(w, g[q][0], acc0);
      acc1 = fmaf(w, g[q][1], acc1);
    }
  }

  const float inv = 0.25f / den;        // per-head normalizer * head-mean
  smem[h][lane * 2]     = acc0 * inv;
  smem[h][lane * 2 + 1] = acc1 * inv;
  __syncthreads();

  if (h == 0) {
    const int c = lane * 2;
    float s0 = smem[0][c] + smem[1][c] + smem[2][c] + smem[3][c];
    float s1 = smem[0][c + 1] + smem[1][c + 1] + smem[2][c + 1] + smem[3][c + 1];
    s0 = elu1(s0 + bias[c]);
    s1 = elu1(s1 + bias[c + 1]);
    if (WF32)
      *(float2*)(out + (size_t)gid * 128 + c) = make_float2(s0, s1);
    if (SPLIT) {
      ushort2 hh, ll;
      hh.x = f2bf(s0); hh.y = f2bf(s1);
      ll.x = f2bf(s0 - bf2f(hh.x)); ll.y = f2bf(s1 - bf2f(hh.y));
      *(ushort2*)(SHo + (size_t)gid * 128 + c) = hh;
      *(ushort2*)(SLo + (size_t)gid * 128 + c) = ll;
    }
  }
}

// ---------------------------------------------------------------------------
extern "C" void kernel_launch(void* const* d_in, const int* in_sizes, int n_in,
                              void* d_out, int out_size, void* d_ws, size_t ws_size,
                              hipStream_t stream)
{
  (void)in_sizes; (void)n_in; (void)out_size; (void)ws_size;

  const float* x  = (const float*)d_in[0];
  const int*   es = (const int*)d_in[1];
  const float *c1_wl=(const float*)d_in[3], *c1_wr=(const float*)d_in[4], *c1_a=(const float*)d_in[5], *c1_b=(const float*)d_in[6];
  const float *c2_wl=(const float*)d_in[7], *c2_wr=(const float*)d_in[8], *c2_a=(const float*)d_in[9], *c2_b=(const float*)d_in[10];
  const float *c3_wl=(const float*)d_in[11],*c3_wr=(const float*)d_in[12],*c3_a=(const float*)d_in[13],*c3_b=(const float*)d_in[14];
  const float *c4_wl=(const float*)d_in[15],*c4_wr=(const float*)d_in[16],*c4_a=(const float*)d_in[17],*c4_b=(const float*)d_in[18];
  const float *r11_wl=(const float*)d_in[19],*r11_wr=(const float*)d_in[20],*r11_a=(const float*)d_in[21],*r11_b=(const float*)d_in[22];
  const float *r12_wl=(const float*)d_in[23],*r12_wr=(const float*)d_in[24],*r12_a=(const float*)d_in[25],*r12_b=(const float*)d_in[26];
  const float *r2_wl=(const float*)d_in[27],*r2_wr=(const float*)d_in[28],*r2_a=(const float*)d_in[29],*r2_b=(const float*)d_in[30];
  const float *f11_wl=(const float*)d_in[31],*f11_wr=(const float*)d_in[32],*f11_a=(const float*)d_in[33],*f11_b=(const float*)d_in[34];
  const float *f2_wl=(const float*)d_in[35],*f2_wr=(const float*)d_in[36],*f2_a=(const float*)d_in[37],*f2_b=(const float*)d_in[38];
  const float *r3_w=(const float*)d_in[39], *r3_b=(const float*)d_in[40];
  const float *f3_w=(const float*)d_in[41], *f3_b=(const float*)d_in[42];
  const float *r4_w=(const float*)d_in[43], *r4_b=(const float*)d_in[44];
  const float *f4_w=(const float*)d_in[45], *f4_b=(const float*)d_in[46];

  // Workspace layout
  float* ws = (float*)d_ws;
  float* GL = ws;                                       // 16.7M f
  float* GR = GL + (size_t)16777216;                    // 16.7M f
  float* A1 = GR + (size_t)16777216;                    // [T,N,64] emb2 fp32
  float* B0 = A1 + (size_t)T_ * N_ * 64;                // [N,128]
  float* B1 = B0 + (size_t)N_ * 128;                    // [N,128]
  ushort* SH  = (ushort*)(B1 + (size_t)N_ * 128);       // split ping
  ushort* SL  = SH + (size_t)8388608;
  ushort* SH2 = SL + (size_t)8388608;                   // split pong
  ushort* SL2 = SH2 + (size_t)8388608;
  ushort* WH  = SL2 + (size_t)8388608;                  // 589824 u16
  ushort* WL  = WH + (size_t)589824;
  uint*  ES16 = (uint*)(WL + (size_t)589824);           // [T,N,16]

  float* recon = (float*)d_out;
  float* fcst  = recon + (size_t)N_ * 64;
  float* emb   = fcst + (size_t)N_ * 64;        // [T,N,64]

  const dim3 blk(256);

  // ---- one-time prep: padded edges, input split, all weight splits ----
  pad_edges<<<dim3(T_ * N_ / 256), blk, 0, stream>>>(es, ES16, T_ * N_);
  split_x<<<dim3(T_ * N_ * 64 / 4 / 256), blk, 0, stream>>>(x, SH, SL, T_ * N_ * 64 / 4);
  WTable tb;
  const float* wls[9] = {c1_wl, c2_wl, c3_wl, c4_wl, r11_wl, r12_wl, r2_wl, f11_wl, f2_wl};
  const float* wrs[9] = {c1_wr, c2_wr, c3_wr, c4_wr, r11_wr, r12_wr, r2_wr, f11_wr, f2_wr};
  const int Ks[9]  = {64, 128, 64, 128, 64, 64, 128, 64, 128};
  const int HCs[9] = {512, 256, 256, 256, 256, 256, 512, 256, 512};
  int woff[9]; int acc_off = 0;
  for (int y = 0; y < 9; y++) {
    tb.wl[y] = wls[y]; tb.wr[y] = wrs[y];
    tb.lgK[y] = __builtin_ctz(Ks[y]); tb.lgHC[y] = __builtin_ctz(HCs[y]);
    woff[y] = acc_off; tb.off[y] = acc_off;
    acc_off += 2 * Ks[y] * HCs[y];
  }
  split_wt_all<<<dim3(512, 9), blk, 0, stream>>>(tb, WH, WL);

  // ---- c1: 64 -> 128 (HC=512); out consumed only via split -> SH2/SL2 ----
  for (int ch = 0; ch < 2; ch++) {
    const int t0 = ch * 4, nt = 4;
    gemm_mfma<<<dim3(N_ / 128, 8, 2 * nt), blk, 0, stream>>>(
        SH + (size_t)t0 * N_ * 64, SL + (size_t)t0 * N_ * 64,
        WH + woff[0], WL + woff[0], GL, GR, N_, 512, 64, nt);
    gat_agg512<true, false, true><<<dim3(nt * N_), blk, 0, stream>>>(
        GL, GR, c1_a, c1_b, ES16 + (size_t)t0 * N_ * 16, nullptr,
        SH2 + (size_t)t0 * N_ * 128, SL2 + (size_t)t0 * N_ * 128);
  }
  // ---- c2: 128 -> 64; emb2 fp32 (concat src) + split -> SH/SL ----
  gemm_mfma<<<dim3(N_ / 128, 4, 2 * T_), blk, 0, stream>>>(
      SH2, SL2, WH + woff[1], WL + woff[1], GL, GR, N_, 256, 128, T_);
  gat_agg256<true, false, true><<<dim3(T_ * N_ / 4), blk, 0, stream>>>(
      GL, GR, c2_a, c2_b, ES16, A1, nullptr, SH, SL);
  // ---- c3: 64 -> 64, concat elu(emb2); out via split -> SH/SL ----
  gemm_mfma<<<dim3(N_ / 128, 4, 2 * T_), blk, 0, stream>>>(
      SH, SL, WH + woff[2], WL + woff[2], GL, GR, N_, 256, 64, T_);
  gat_agg256<true, true, false><<<dim3(T_ * N_ / 4), blk, 0, stream>>>(
      GL, GR, c3_a, c3_b, ES16, nullptr, A1, SH, SL);
  // ---- c4: 128 -> 64 -> emb (d_out) + split -> SH2/SL2 ----
  gemm_mfma<<<dim3(N_ / 128, 4, 2 * T_), blk, 0, stream>>>(
      SH, SL, WH + woff[3], WL + woff[3], GL, GR, N_, 256, 128, T_);
  gat_agg256<true, false, true><<<dim3(T_ * N_ / 4), blk, 0, stream>>>(
      GL, GR, c4_a, c4_b, ES16, emb, nullptr, SH2, SL2);

  // ---- reconstruction branch (edges at t = 7; emb split slice 7) ----
  const uint* esR = ES16 + (size_t)7 * N_ * 16;
  gemm_mfma<<<dim3(N_ / 128, 4, 2), blk, 0, stream>>>(
      SH2 + (size_t)7 * N_ * 64, SL2 + (size_t)7 * N_ * 64,
      WH + woff[4], WL + woff[4], GL, GR, N_, 256, 64, 1);
  gat_agg256<false, false, true><<<dim3(N_ / 4), blk, 0, stream>>>(
      GL, GR, r11_a, r11_b, esR, B0, nullptr, SH, SL);
  gemm_mfma<<<dim3(N_ / 128, 4, 2), blk, 0, stream>>>(
      SH, SL, WH + woff[5], WL + woff[5], GL, GR, N_, 256, 64, 1);
  gat_agg256<false, true, false><<<dim3(N_ / 4), blk, 0, stream>>>(
      GL, GR, r12_a, r12_b, esR, nullptr, B0, SH, SL);
  gemm_mfma<<<dim3(N_ / 128, 8, 2), blk, 0, stream>>>(
      SH, SL, WH + woff[6], WL + woff[6], GL, GR, N_, 512, 128, 1);
  gat_agg512<false, true, false><<<dim3(N_), blk, 0, stream>>>(
      GL, GR, r2_a, r2_b, esR, B0, nullptr, nullptr);
  gemm_k<1><<<dim3(N_ / 64, 1, 1), blk, 0, stream>>>(B0, r3_w, B1, r3_b, N_, 64, 128);
  gemm_k<2><<<dim3(N_ / 64, 1, 1), blk, 0, stream>>>(B1, r4_w, recon, r4_b, N_, 64, 64);

  // ---- forecasting branch (edges at t = 6; emb split slice 6) ----
  const uint* esF = ES16 + (size_t)6 * N_ * 16;
  gemm_mfma<<<dim3(N_ / 128, 4, 2), blk, 0, stream>>>(
      SH2 + (size_t)6 * N_ * 64, SL2 + (size_t)6 * N_ * 64,
      WH + woff[7], WL + woff[7], GL, GR, N_, 256, 64, 1);
  gat_agg256<false, false, true><<<dim3(N_ / 4), blk, 0, stream>>>(
      GL, GR, f11_a, f11_b, esF, B0, nullptr, SH, SL);
  gemm_mfma<<<dim3(N_ / 128, 4, 2), blk, 0, stream>>>(
      SH, SL, WH + woff[5], WL + woff[5], GL, GR, N_, 256, 64, 1);
  gat_agg256<false, true, false><<<dim3(N_ / 4), blk, 0, stream>>>(
      GL, GR, r12_a, r12_b, esF, nullptr, B0, SH, SL);
  gemm_mfma<<<dim3(N_ / 128, 8, 2), blk, 0, stream>>>(
      SH, SL, WH + woff[8], WL + woff[8], GL, GR, N_, 512, 128, 1);
  gat_agg512<false, true, false><<<dim3(N_), blk, 0, stream>>>(
      GL, GR, f2_a, f2_b, esF, B0, nullptr, nullptr);
  gemm_k<1><<<dim3(N_ / 64, 1, 1), blk, 0, stream>>>(B0, f3_w, B1, f3_b, N_, 64, 128);
  gemm_k<2><<<dim3(N_ / 64, 1, 1), blk, 0, stream>>>(B1, f4_w, fcst, f4_b, N_, 64, 64);
}

// Round 12
// 905.180 us; speedup vs baseline: 1.5553x; 1.0573x over previous
//
#include <hip/hip_runtime.h>
#include <cmath>

// Problem constants (from reference setup_inputs)
constexpr int T_   = 8;
constexpr int N_   = 8192;
constexpr int DEG_ = 15;
constexpr int E_   = N_ * (DEG_ + 1);   // 131072 edges per timestep
constexpr float L2E_ = 1.44269504f;

// fast ELU: expm1 via exp2 (abs err ~1e-7, threshold 7e-4)
__device__ __forceinline__ float elu1(float v) {
  return v > 0.f ? v : exp2f(v * L2E_) - 1.f;
}

typedef __attribute__((ext_vector_type(8))) short bf16x8;
typedef __attribute__((ext_vector_type(4))) float f32x4;

__device__ __forceinline__ ushort f2bf(float x) {
  uint u = __float_as_uint(x);
  return (ushort)((u + 0x7FFFu + ((u >> 16) & 1u)) >> 16);
}
__device__ __forceinline__ float bf2f(ushort h) {
  return __uint_as_float(((uint)h) << 16);
}
__device__ __forceinline__ void wsplit4(ushort* SH, ushort* SL, size_t idx, const float* o) {
  ushort4 hh, ll;
  hh.x = f2bf(o[0]); hh.y = f2bf(o[1]); hh.z = f2bf(o[2]); hh.w = f2bf(o[3]);
  ll.x = f2bf(o[0] - bf2f(hh.x)); ll.y = f2bf(o[1] - bf2f(hh.y));
  ll.z = f2bf(o[2] - bf2f(hh.z)); ll.w = f2bf(o[3] - bf2f(hh.w));
  *(ushort4*)(SH + idx) = hh;
  *(ushort4*)(SL + idx) = ll;
}

// v_add with DPP row_ror: sum over each 16-lane row after steps 1,2,4,8.
template<int CTRL>
__device__ __forceinline__ float dpp_add(float x) {
  const int t = __builtin_amdgcn_mov_dpp(__float_as_int(x), CTRL, 0xf, 0xf, true);
  return x + __int_as_float(t);
}
__device__ __forceinline__ float row_reduce16(float x) {
  x = dpp_add<0x121>(x);   // row_ror:1
  x = dpp_add<0x122>(x);   // row_ror:2
  x = dpp_add<0x124>(x);   // row_ror:4
  x = dpp_add<0x128>(x);   // row_ror:8
  return x;
}

// ---------------------------------------------------------------------------
// pad_edges: es[T][N*DEG] -> es16[T][N][16] (15 edges + self loop), uint.
// ---------------------------------------------------------------------------
__global__ __launch_bounds__(256) void pad_edges(
    const int* __restrict__ es, uint* __restrict__ es16, int total)
{
  const int idx = blockIdx.x * 256 + threadIdx.x;
  if (idx >= total) return;
  const int t = idx >> 13, i = idx & (N_ - 1);
  const int* e = es + (size_t)t * E_ + (size_t)i * DEG_;
  uint o[16];
  #pragma unroll
  for (int k = 0; k < DEG_; k++) o[k] = (uint)e[k];
  o[15] = (uint)i;
  uint4* dst = (uint4*)(es16 + (size_t)idx * 16);
  dst[0] = make_uint4(o[0], o[1], o[2], o[3]);
  dst[1] = make_uint4(o[4], o[5], o[6], o[7]);
  dst[2] = make_uint4(o[8], o[9], o[10], o[11]);
  dst[3] = make_uint4(o[12], o[13], o[14], o[15]);
}

// ---------------------------------------------------------------------------
// split_x: fp32 array -> hi/lo bf16 arrays (same layout). 4 elems/thread.
// ---------------------------------------------------------------------------
__global__ __launch_bounds__(256) void split_x(
    const float* __restrict__ X, ushort* __restrict__ XH, ushort* __restrict__ XL, int n4)
{
  const int i = blockIdx.x * 256 + threadIdx.x;
  if (i >= n4) return;
  const float4 v = ((const float4*)X)[i];
  const float o[4] = {v.x, v.y, v.z, v.w};
  wsplit4(XH, XL, (size_t)i * 4, o);
}

// ---------------------------------------------------------------------------
// split_wt_all: all 9 weight pairs in one launch. grid.y = pair index.
// ---------------------------------------------------------------------------
struct WTable {
  const float* wl[9]; const float* wr[9];
  int lgK[9]; int lgHC[9]; int off[9];
};
__global__ __launch_bounds__(256) void split_wt_all(
    WTable tb, ushort* __restrict__ WH, ushort* __restrict__ WL)
{
  const int y = blockIdx.y;
  const int lgK = tb.lgK[y], lgHC = tb.lgHC[y];
  const int n2 = 2 << (lgK + lgHC);
  const int idx = blockIdx.x * 256 + threadIdx.x;
  if (idx >= n2) return;
  const int k = idx & ((1 << lgK) - 1);
  const int n = (idx >> lgK) & ((1 << lgHC) - 1);
  const int s = idx >> (lgK + lgHC);
  const float* W = s ? tb.wr[y] : tb.wl[y];
  const float v = W[((size_t)k << lgHC) + n];
  const ushort h = f2bf(v);
  WH[tb.off[y] + idx] = h;
  WL[tb.off[y] + idx] = f2bf(v - bf2f(h));
}

// ---------------------------------------------------------------------------
// MFMA GEMM (split-bf16): C = A @ W, A hi/lo [nt][M][lda] bf16 (first K cols
// used), W hi/lo [2][Ncol][K] bf16 at WH+wo (wo = woffA, or woffB for t==1).
// x.w ~= ah.wh + ah.wl + al.wh.  BM=128, BN=64, BK=32; 256 thr = 4 waves.
// ---------------------------------------------------------------------------
__global__ __launch_bounds__(256) void gemm_mfma(
    const ushort* __restrict__ Ah, const ushort* __restrict__ Al,
    const ushort* __restrict__ WHb, const ushort* __restrict__ WLb,
    float* __restrict__ Cl, float* __restrict__ Cr,
    int M, int Ncol, int K, int lda, int nt, int woffA, int woffB)
{
  __shared__ alignas(16) ushort lAh[4 * 1032];
  __shared__ alignas(16) ushort lAl[4 * 1032];
  __shared__ alignas(16) ushort lBh[4 * 520];
  __shared__ alignas(16) ushort lBl[4 * 520];

  const int z = blockIdx.z;
  const int t = (z < nt) ? z : z - nt;
  const int side = (z < nt) ? 0 : 1;
  const int wo = (t == 1) ? woffB : woffA;
  const ushort* __restrict__ Bh = WHb + wo + (size_t)side * Ncol * K;
  const ushort* __restrict__ Bl = WLb + wo + (size_t)side * Ncol * K;
  float* __restrict__ C = (side ? Cr : Cl) + (size_t)t * M * Ncol;
  const size_t aoff = (size_t)t * M * lda;

  const int bm = blockIdx.x * 128, bn = blockIdx.y * 64;
  const int tid = threadIdx.x;
  const int wid = tid >> 6, lane = tid & 63;
  const int l15 = lane & 15, lk = lane >> 4;

  f32x4 acc[2][4] = {};

  for (int k0 = 0; k0 < K; k0 += 32) {
    #pragma unroll
    for (int c = 0; c < 2; c++) {
      const int ch = tid + c * 256;
      const int row = ch >> 2, kc = ch & 3;
      const size_t ga = aoff + (size_t)(bm + row) * lda + (k0 + kc * 8);
      *(uint4*)&lAh[kc * 1032 + row * 8] = *(const uint4*)(Ah + ga);
      *(uint4*)&lAl[kc * 1032 + row * 8] = *(const uint4*)(Al + ga);
    }
    {
      const int col = tid >> 2, kc = tid & 3;
      const size_t gb = (size_t)(bn + col) * K + (k0 + kc * 8);
      *(uint4*)&lBh[kc * 520 + col * 8] = *(const uint4*)(Bh + gb);
      *(uint4*)&lBl[kc * 520 + col * 8] = *(const uint4*)(Bl + gb);
    }
    __syncthreads();

    bf16x8 ah[2], al[2], bh4[4], bl4[4];
    const int r0 = wid * 32;
    #pragma unroll
    for (int rf = 0; rf < 2; rf++) {
      const int ro = (r0 + rf * 16 + l15) * 8;
      ah[rf] = *(const bf16x8*)&lAh[lk * 1032 + ro];
      al[rf] = *(const bf16x8*)&lAl[lk * 1032 + ro];
    }
    #pragma unroll
    for (int cf = 0; cf < 4; cf++) {
      const int co = (cf * 16 + l15) * 8;
      bh4[cf] = *(const bf16x8*)&lBh[lk * 520 + co];
      bl4[cf] = *(const bf16x8*)&lBl[lk * 520 + co];
    }
    #pragma unroll
    for (int rf = 0; rf < 2; rf++)
      #pragma unroll
      for (int cf = 0; cf < 4; cf++) {
        acc[rf][cf] = __builtin_amdgcn_mfma_f32_16x16x32_bf16(ah[rf], bh4[cf], acc[rf][cf], 0, 0, 0);
        acc[rf][cf] = __builtin_amdgcn_mfma_f32_16x16x32_bf16(ah[rf], bl4[cf], acc[rf][cf], 0, 0, 0);
        acc[rf][cf] = __builtin_amdgcn_mfma_f32_16x16x32_bf16(al[rf], bh4[cf], acc[rf][cf], 0, 0, 0);
      }
    __syncthreads();
  }

  #pragma unroll
  for (int rf = 0; rf < 2; rf++)
    #pragma unroll
    for (int cf = 0; cf < 4; cf++) {
      const int col = bn + cf * 16 + l15;
      #pragma unroll
      for (int reg = 0; reg < 4; reg++) {
        const int row = bm + wid * 32 + rf * 16 + lk * 4 + reg;
        C[(size_t)row * Ncol + col] = acc[rf][cf][reg];
      }
    }
}

// ---------------------------------------------------------------------------
// Small fp32 GEMM, 2-batch (z = branch). 64x64 tile, 4x4/thread.
// ---------------------------------------------------------------------------
struct GK2 {
  const float* A[2]; const float* B[2]; float* C[2]; const float* bias[2];
};
template<int EPI>   // 1 = +bias tanh, 2 = +bias
__global__ __launch_bounds__(256) void gemm_k2(GK2 p, int M, int Ncol, int K)
{
  __shared__ float As[16][68];
  __shared__ float Bs[16][64];

  const int z = blockIdx.z;
  const float* __restrict__ A = p.A[z];
  const float* __restrict__ B = p.B[z];
  float* __restrict__ C = p.C[z];
  const float* __restrict__ bias = p.bias[z];

  const int tid = threadIdx.x;
  const int tx = tid & 15, ty = tid >> 4;
  const int bm = blockIdx.x * 64, bn = blockIdx.y * 64;

  const int arow = tid >> 2;
  const int akc  = (tid & 3) * 4;
  const int brow = tid >> 4;
  const int bc4  = (tid & 15) * 4;

  float acc[4][4];
  #pragma unroll
  for (int i = 0; i < 4; i++)
    #pragma unroll
    for (int j = 0; j < 4; j++) acc[i][j] = 0.f;

  for (int k0 = 0; k0 < K; k0 += 16) {
    const float4 va = *(const float4*)(A + (size_t)(bm + arow) * K + (k0 + akc));
    const float4 vb = *(const float4*)(B + (size_t)(k0 + brow) * Ncol + (bn + bc4));
    As[akc + 0][arow] = va.x; As[akc + 1][arow] = va.y;
    As[akc + 2][arow] = va.z; As[akc + 3][arow] = va.w;
    *(float4*)&Bs[brow][bc4] = vb;
    __syncthreads();
    #pragma unroll
    for (int kk = 0; kk < 16; kk++) {
      const float4 av = *(const float4*)&As[kk][ty * 4];
      const float4 bv = *(const float4*)&Bs[kk][tx * 4];
      const float a4[4] = {av.x, av.y, av.z, av.w};
      const float b4[4] = {bv.x, bv.y, bv.z, bv.w};
      #pragma unroll
      for (int i = 0; i < 4; i++)
        #pragma unroll
        for (int j = 0; j < 4; j++)
          acc[i][j] = fmaf(a4[i], b4[j], acc[i][j]);
    }
    __syncthreads();
  }

  #pragma unroll
  for (int i = 0; i < 4; i++) {
    const int row = bm + ty * 4 + i;
    const int col = bn + tx * 4;
    float v[4] = {acc[i][0], acc[i][1], acc[i][2], acc[i][3]};
    #pragma unroll
    for (int j = 0; j < 4; j++) v[j] += bias[col + j];
    if (EPI == 1) {
      #pragma unroll
      for (int j = 0; j < 4; j++) v[j] = tanhf(v[j]);
    }
    *(float4*)(C + (size_t)row * Ncol + col) = make_float4(v[0], v[1], v[2], v[3]);
  }
}

// ---------------------------------------------------------------------------
// GATv2 aggregation, HC=256 (cout=64): 1 wave per node, 4 nodes/block.
// SWZ: t = bid&7 (XCD pin, main T=8 layers). BATCH2: t = bid>>11 (branch
// 2-batch; per-t aw/bias). DUP: lanes 16-31 also write split(elu(o)) at
// cols 64-127 (pre-computed concat half for the NEXT layer). WF32: fp32 out.
// Split written at row stride OSTR.
// ---------------------------------------------------------------------------
template<bool SWZ, bool BATCH2, bool DUP, bool WF32, int OSTR>
__global__ __launch_bounds__(256) void gat_agg256(
    const float* __restrict__ GL, const float* __restrict__ GR,
    const float* __restrict__ aw0, const float* __restrict__ aw1,
    const float* __restrict__ b0, const float* __restrict__ b1,
    const uint* __restrict__ es16, float* __restrict__ out,
    ushort* __restrict__ SHo, ushort* __restrict__ SLo)
{
  const int lane = threadIdx.x & 63;
  const int wid  = threadIdx.x >> 6;
  const int bid  = blockIdx.x;
  const int t    = SWZ ? (bid & 7) : (BATCH2 ? (bid >> 11) : 0);
  const int ib   = SWZ ? (bid >> 3) : (BATCH2 ? (bid & 2047) : bid);
  const int gid  = t * N_ + ib * 4 + wid;
  const float* __restrict__ aw_  = (BATCH2 && t == 1) ? aw1 : aw0;
  const float* __restrict__ bias = (BATCH2 && t == 1) ? b1 : b0;

  const float* __restrict__ gl = GL + (size_t)t * N_ * 256;
  const uint*  __restrict__ ep = es16 + (size_t)gid * 16;
  const uint lo16 = (uint)lane << 4;

  float gr[4], a6[4], a4c[4];
  {
    const float4 gv = *(const float4*)(GR + (size_t)gid * 256 + lane * 4);
    const float4 av = *(const float4*)(aw_ + lane * 4);
    gr[0] = gv.x; gr[1] = gv.y; gr[2] = gv.z; gr[3] = gv.w;
    a6[0] = 0.6f * L2E_ * av.x; a6[1] = 0.6f * L2E_ * av.y;
    a6[2] = 0.6f * L2E_ * av.z; a6[3] = 0.6f * L2E_ * av.w;
    a4c[0] = 0.4f * L2E_ * av.x; a4c[1] = 0.4f * L2E_ * av.y;
    a4c[2] = 0.4f * L2E_ * av.z; a4c[3] = 0.4f * L2E_ * av.w;
  }

  float acc[4] = {0.f, 0.f, 0.f, 0.f};
  float den = 0.f, m = 0.f;

  #pragma unroll
  for (int b = 0; b < 4; b++) {
    const uint4 j4 = *(const uint4*)(ep + b * 4);
    uint off[4];
    off[0] = (j4.x << 10) + lo16;
    off[1] = (j4.y << 10) + lo16;
    off[2] = (j4.z << 10) + lo16;
    off[3] = (j4.w << 10) + lo16;
    float g[4][4];
    #pragma unroll
    for (int q = 0; q < 4; q++) {
      const float4 v = *(const float4*)((const char*)gl + off[q]);
      g[q][0] = v.x; g[q][1] = v.y; g[q][2] = v.z; g[q][3] = v.w;
    }
    float p[4];
    #pragma unroll
    for (int q = 0; q < 4; q++) {
      float s = 0.f;
      #pragma unroll
      for (int u = 0; u < 4; u++) {
        const float z = g[q][u] + gr[u];
        s = fmaf(z, a6[u], s);
        s = fmaf(fabsf(z), a4c[u], s);
      }
      p[q] = s;
    }
    #pragma unroll
    for (int q = 0; q < 4; q++) p[q] = row_reduce16(p[q]);

    const float bmax = fmaxf(fmaxf(p[0], p[1]), fmaxf(p[2], p[3]));
    if (b == 0) {
      m = bmax;
    } else {
      const float nm = fmaxf(m, bmax);
      const float sc = exp2f(m - nm);
      den *= sc;
      #pragma unroll
      for (int u = 0; u < 4; u++) acc[u] *= sc;
      m = nm;
    }
    #pragma unroll
    for (int q = 0; q < 4; q++) {
      const float w = exp2f(p[q] - m);
      den += w;
      #pragma unroll
      for (int u = 0; u < 4; u++) acc[u] = fmaf(w, g[q][u], acc[u]);
    }
  }

  const float inv = 0.25f / den;
  #pragma unroll
  for (int u = 0; u < 4; u++) acc[u] *= inv;
  #pragma unroll
  for (int u = 0; u < 4; u++) {
    acc[u] += __shfl_xor(acc[u], 16);
    acc[u] += __shfl_xor(acc[u], 32);
  }

  if (lane < 16) {
    float o[4];
    #pragma unroll
    for (int u = 0; u < 4; u++)
      o[u] = elu1(acc[u] + bias[lane * 4 + u]);
    if (WF32)
      *(float4*)(out + (size_t)gid * OSTR + lane * 4) = make_float4(o[0], o[1], o[2], o[3]);
    wsplit4(SHo, SLo, (size_t)gid * OSTR + lane * 4, o);
  } else if (DUP && lane < 32) {
    const int q = lane - 16;   // lanes 16-31 hold same acc (channels q*4..)
    float o[4];
    #pragma unroll
    for (int u = 0; u < 4; u++)
      o[u] = elu1(elu1(acc[u] + bias[q * 4 + u]));   // concat half = elu(this-layer out)
    wsplit4(SHo, SLo, (size_t)gid * OSTR + 64 + q * 4, o);
  }
}

// ---------------------------------------------------------------------------
// GATv2 aggregation, HC=512 (cout=128): 1 node/block, 1 head/wave, lane owns
// 2 ch (24-VGPR shape). SWZ: c1 nt=4 chunk XCD pin. BATCH2: branch 2-batch
// (t = bid>>13, per-t aw/bias).
// ---------------------------------------------------------------------------
template<bool SWZ, bool BATCH2, bool WF32, bool SPLIT>
__global__ __launch_bounds__(256) void gat_agg512(
    const float* __restrict__ GL, const float* __restrict__ GR,
    const float* __restrict__ aw0, const float* __restrict__ aw1,
    const float* __restrict__ b0, const float* __restrict__ b1,
    const uint* __restrict__ es16, float* __restrict__ out,
    ushort* __restrict__ SHo, ushort* __restrict__ SLo)
{
  __shared__ float smem[4][128];

  const int lane = threadIdx.x & 63;
  const int h    = threadIdx.x >> 6;
  const int bid  = blockIdx.x;
  int t, i;
  if (SWZ) {                 // nt=4 chunk: bid in [0, 32768)
    const int xcd = bid & 7;
    t = xcd >> 1;
    i = ((bid >> 3) << 1) | (xcd & 1);
  } else if (BATCH2) {       // bid in [0, 16384)
    t = bid >> 13; i = bid & (N_ - 1);
  } else {
    t = 0; i = bid;
  }
  const int gid = t * N_ + i;
  const float* __restrict__ aw_  = (BATCH2 && t == 1) ? aw1 : aw0;
  const float* __restrict__ bias = (BATCH2 && t == 1) ? b1 : b0;

  const float* __restrict__ gl = GL + (size_t)t * N_ * 512;
  const uint*  __restrict__ ep = es16 + (size_t)gid * 16;
  const int cb = h * 128 + lane * 2;
  const uint cbo = (uint)cb << 2;

  float gr0, gr1, a60, a61, a40, a41;
  {
    const float2 gv = *(const float2*)(GR + (size_t)gid * 512 + cb);
    const float2 av = *(const float2*)(aw_ + cb);
    gr0 = gv.x; gr1 = gv.y;
    a60 = 0.6f * L2E_ * av.x; a61 = 0.6f * L2E_ * av.y;
    a40 = 0.4f * L2E_ * av.x; a41 = 0.4f * L2E_ * av.y;
  }

  float acc0 = 0.f, acc1 = 0.f, den = 0.f, m = 0.f;

  #pragma unroll
  for (int b = 0; b < 4; b++) {
    const uint4 j4 = *(const uint4*)(ep + b * 4);
    uint off[4];
    off[0] = (j4.x << 11) + cbo;
    off[1] = (j4.y << 11) + cbo;
    off[2] = (j4.z << 11) + cbo;
    off[3] = (j4.w << 11) + cbo;
    float g[4][2];
    #pragma unroll
    for (int q = 0; q < 4; q++) {
      const float2 v = *(const float2*)((const char*)gl + off[q]);
      g[q][0] = v.x; g[q][1] = v.y;
    }
    float p[4];
    #pragma unroll
    for (int q = 0; q < 4; q++) {
      const float z0 = g[q][0] + gr0;
      const float z1 = g[q][1] + gr1;
      float s = z0 * a60;
      s = fmaf(fabsf(z0), a40, s);
      s = fmaf(z1, a61, s);
      s = fmaf(fabsf(z1), a41, s);
      p[q] = s;
    }
    #pragma unroll
    for (int q = 0; q < 4; q++) {
      p[q] = row_reduce16(p[q]);
      p[q] += __shfl_xor(p[q], 16);
      p[q] += __shfl_xor(p[q], 32);
    }
    const float bmax = fmaxf(fmaxf(p[0], p[1]), fmaxf(p[2], p[3]));
    if (b == 0) {
      m = bmax;
    } else {
      const float nm = fmaxf(m, bmax);
      const float sc = exp2f(m - nm);
      den *= sc; acc0 *= sc; acc1 *= sc;
      m = nm;
    }
    #pragma unroll
    for (int q = 0; q < 4; q++) {
      const float w = exp2f(p[q] - m);
      den += w;
      acc0 = fmaf(w, g[q][0], acc0);
      acc1 = fmaf(w, g[q][1], acc1);
    }
  }

  const float inv = 0.25f / den;
  smem[h][lane * 2]     = acc0 * inv;
  smem[h][lane * 2 + 1] = acc1 * inv;
  __syncthreads();

  if (h == 0) {
    const int c = lane * 2;
    float s0 = smem[0][c] + smem[1][c] + smem[2][c] + smem[3][c];
    float s1 = smem[0][c + 1] + smem[1][c + 1] + smem[2][c + 1] + smem[3][c + 1];
    s0 = elu1(s0 + bias[c]);
    s1 = elu1(s1 + bias[c + 1]);
    if (WF32)
      *(float2*)(out + (size_t)gid * 128 + c) = make_float2(s0, s1);
    if (SPLIT) {
      ushort2 hh, ll;
      hh.x = f2bf(s0); hh.y = f2bf(s1);
      ll.x = f2bf(s0 - bf2f(hh.x)); ll.y = f2bf(s1 - bf2f(hh.y));
      *(ushort2*)(SHo + (size_t)gid * 128 + c) = hh;
      *(ushort2*)(SLo + (size_t)gid * 128 + c) = ll;
    }
  }
}

// ---------------------------------------------------------------------------
extern "C" void kernel_launch(void* const* d_in, const int* in_sizes, int n_in,
                              void* d_out, int out_size, void* d_ws, size_t ws_size,
                              hipStream_t stream)
{
  (void)in_sizes; (void)n_in; (void)out_size; (void)ws_size;

  const float* x  = (const float*)d_in[0];
  const int*   es = (const int*)d_in[1];
  const float *c1_wl=(const float*)d_in[3], *c1_wr=(const float*)d_in[4], *c1_a=(const float*)d_in[5], *c1_b=(const float*)d_in[6];
  const float *c2_wl=(const float*)d_in[7], *c2_wr=(const float*)d_in[8], *c2_a=(const float*)d_in[9], *c2_b=(const float*)d_in[10];
  const float *c3_wl=(const float*)d_in[11],*c3_wr=(const float*)d_in[12],*c3_a=(const float*)d_in[13],*c3_b=(const float*)d_in[14];
  const float *c4_wl=(const float*)d_in[15],*c4_wr=(const float*)d_in[16],*c4_a=(const float*)d_in[17],*c4_b=(const float*)d_in[18];
  const float *r11_wl=(const float*)d_in[19],*r11_wr=(const float*)d_in[20],*r11_a=(const float*)d_in[21],*r11_b=(const float*)d_in[22];
  const float *r12_wl=(const float*)d_in[23],*r12_wr=(const float*)d_in[24],*r12_a=(const float*)d_in[25],*r12_b=(const float*)d_in[26];
  const float *r2_wl=(const float*)d_in[27],*r2_wr=(const float*)d_in[28],*r2_a=(const float*)d_in[29],*r2_b=(const float*)d_in[30];
  const float *f11_wl=(const float*)d_in[31],*f11_wr=(const float*)d_in[32],*f11_a=(const float*)d_in[33],*f11_b=(const float*)d_in[34];
  const float *f2_wl=(const float*)d_in[35],*f2_wr=(const float*)d_in[36],*f2_a=(const float*)d_in[37],*f2_b=(const float*)d_in[38];
  const float *r3_w=(const float*)d_in[39], *r3_b=(const float*)d_in[40];
  const float *f3_w=(const float*)d_in[41], *f3_b=(const float*)d_in[42];
  const float *r4_w=(const float*)d_in[43], *r4_b=(const float*)d_in[44];
  const float *f4_w=(const float*)d_in[45], *f4_b=(const float*)d_in[46];

  // Workspace layout
  float* ws = (float*)d_ws;
  float* GL = ws;                                       // 16.7M f
  float* GR = GL + (size_t)16777216;                    // 16.7M f
  float* B0 = GR + (size_t)16777216;                    // [2][N][128]
  float* B1 = B0 + (size_t)2 * N_ * 128;                // [2][N][64]
  ushort* SH  = (ushort*)(B1 + (size_t)2 * N_ * 64);    // ping [T,N,128] cap
  ushort* SL  = SH + (size_t)8388608;
  ushort* SH2 = SL + (size_t)8388608;                   // pong [T,N,128] cap
  ushort* SL2 = SH2 + (size_t)8388608;
  ushort* WH  = SL2 + (size_t)8388608;                  // 589824 u16
  ushort* WL  = WH + (size_t)589824;
  uint*  ES16 = (uint*)(WL + (size_t)589824);           // [T,N,16]

  float* recon = (float*)d_out;
  float* fcst  = recon + (size_t)N_ * 64;
  float* emb   = fcst + (size_t)N_ * 64;                // [T,N,64]

  const dim3 blk(256);

  // ---- one-time prep ----
  pad_edges<<<dim3(T_ * N_ / 256), blk, 0, stream>>>(es, ES16, T_ * N_);
  split_x<<<dim3(T_ * N_ * 64 / 4 / 256), blk, 0, stream>>>(x, SH, SL, T_ * N_ * 64 / 4);
  WTable tb;
  const float* wls[9] = {c1_wl, c2_wl, c3_wl, c4_wl, r11_wl, r12_wl, r2_wl, f11_wl, f2_wl};
  const float* wrs[9] = {c1_wr, c2_wr, c3_wr, c4_wr, r11_wr, r12_wr, r2_wr, f11_wr, f2_wr};
  const int Ks[9]  = {64, 128, 64, 128, 64, 64, 128, 64, 128};
  const int HCs[9] = {512, 256, 256, 256, 256, 256, 512, 256, 512};
  int woff[9]; int acc_off = 0;
  for (int y = 0; y < 9; y++) {
    tb.wl[y] = wls[y]; tb.wr[y] = wrs[y];
    tb.lgK[y] = __builtin_ctz(Ks[y]); tb.lgHC[y] = __builtin_ctz(HCs[y]);
    woff[y] = acc_off; tb.off[y] = acc_off;
    acc_off += 2 * Ks[y] * HCs[y];
  }
  split_wt_all<<<dim3(512, 9), blk, 0, stream>>>(tb, WH, WL);

  // ---- c1: 64 -> 128 (HC=512); out via split -> pong [T,N,128] ----
  for (int ch = 0; ch < 2; ch++) {
    const int t0 = ch * 4, nt = 4;
    gemm_mfma<<<dim3(N_ / 128, 8, 2 * nt), blk, 0, stream>>>(
        SH + (size_t)t0 * N_ * 64, SL + (size_t)t0 * N_ * 64,
        WH, WL, GL, GR, N_, 512, 64, 64, nt, woff[0], woff[0]);
    gat_agg512<true, false, false, true><<<dim3(nt * N_), blk, 0, stream>>>(
        GL, GR, c1_a, c1_a, c1_b, c1_b, ES16 + (size_t)t0 * N_ * 16, nullptr,
        SH2 + (size_t)t0 * N_ * 128, SL2 + (size_t)t0 * N_ * 128);
  }
  // ---- c2: 128 -> 64; split + concat-half(DUP) -> ping [T,N,128] ----
  gemm_mfma<<<dim3(N_ / 128, 4, 2 * T_), blk, 0, stream>>>(
      SH2, SL2, WH, WL, GL, GR, N_, 256, 128, 128, T_, woff[1], woff[1]);
  gat_agg256<true, false, true, false, 128><<<dim3(T_ * N_ / 4), blk, 0, stream>>>(
      GL, GR, c2_a, c2_a, c2_b, c2_b, ES16, nullptr, SH, SL);
  // ---- c3: 64 -> 64 (reads ping cols 0-63); writes ping cols 0-63 ----
  gemm_mfma<<<dim3(N_ / 128, 4, 2 * T_), blk, 0, stream>>>(
      SH, SL, WH, WL, GL, GR, N_, 256, 64, 128, T_, woff[2], woff[2]);
  gat_agg256<true, false, false, false, 128><<<dim3(T_ * N_ / 4), blk, 0, stream>>>(
      GL, GR, c3_a, c3_a, c3_b, c3_b, ES16, nullptr, SH, SL);
  // ---- c4: 128 -> 64 (reads ping full 128) -> emb (d_out) + split -> pong ----
  gemm_mfma<<<dim3(N_ / 128, 4, 2 * T_), blk, 0, stream>>>(
      SH, SL, WH, WL, GL, GR, N_, 256, 128, 128, T_, woff[3], woff[3]);
  gat_agg256<true, false, false, true, 64><<<dim3(T_ * N_ / 4), blk, 0, stream>>>(
      GL, GR, c4_a, c4_a, c4_b, c4_b, ES16, emb, SH2, SL2);

  // ---- branches, 2-batched (t=0: forecast/slice 6, t=1: recon/slice 7) ----
  const uint* esB = ES16 + (size_t)6 * N_ * 16;
  // layer 11: emb slices [6,7] -> 256; split + DUP concat half -> ping [2][N][128]
  gemm_mfma<<<dim3(N_ / 128, 4, 4), blk, 0, stream>>>(
      SH2 + (size_t)6 * N_ * 64, SL2 + (size_t)6 * N_ * 64,
      WH, WL, GL, GR, N_, 256, 64, 64, 2, woff[7], woff[4]);
  gat_agg256<false, true, true, false, 128><<<dim3(2 * N_ / 4), blk, 0, stream>>>(
      GL, GR, f11_a, r11_a, f11_b, r11_b, esB, nullptr, SH, SL);
  // layer 12 (shared weights): reads ping cols 0-63; writes ping cols 0-63
  gemm_mfma<<<dim3(N_ / 128, 4, 4), blk, 0, stream>>>(
      SH, SL, WH, WL, GL, GR, N_, 256, 64, 128, 2, woff[5], woff[5]);
  gat_agg256<false, true, false, false, 128><<<dim3(2 * N_ / 4), blk, 0, stream>>>(
      GL, GR, r12_a, r12_a, r12_b, r12_b, esB, nullptr, SH, SL);
  // layer 2: reads ping full 128 -> 512; agg -> B0 fp32 [2][N][128]
  gemm_mfma<<<dim3(N_ / 128, 8, 4), blk, 0, stream>>>(
      SH, SL, WH, WL, GL, GR, N_, 512, 128, 128, 2, woff[8], woff[6]);
  gat_agg512<false, true, true, false><<<dim3(2 * N_), blk, 0, stream>>>(
      GL, GR, f2_a, r2_a, f2_b, r2_b, esB, B0, nullptr, nullptr);
  // heads: tanh(B0 @ w3 + b3) @ w4 + b4
  GK2 p3;
  p3.A[0] = B0; p3.A[1] = B0 + (size_t)N_ * 128;
  p3.B[0] = f3_w; p3.B[1] = r3_w;
  p3.C[0] = B1; p3.C[1] = B1 + (size_t)N_ * 64;
  p3.bias[0] = f3_b; p3.bias[1] = r3_b;
  gemm_k2<1><<<dim3(N_ / 64, 1, 2), blk, 0, stream>>>(p3, N_, 64, 128);
  GK2 p4;
  p4.A[0] = B1; p4.A[1] = B1 + (size_t)N_ * 64;
  p4.B[0] = f4_w; p4.B[1] = r4_w;
  p4.C[0] = fcst; p4.C[1] = recon;
  p4.bias[0] = f4_b; p4.bias[1] = r4_b;
  gemm_k2<2><<<dim3(N_ / 64, 1, 2), blk, 0, stream>>>(p4, N_, 64, 64);
}